// Round 9
// baseline (1096.786 us; speedup 1.0000x reference)
//
#include <hip/hip_runtime.h>
#include <hip/hip_bf16.h>
#include <math.h>

typedef __bf16 bf16_t;
typedef float floatx4 __attribute__((ext_vector_type(4)));
typedef bf16_t bf16x8 __attribute__((ext_vector_type(8)));

typedef __attribute__((address_space(1))) void g_void;
typedef __attribute__((address_space(3))) void lds_void;

__device__ __forceinline__ void ldg_lds16(const bf16_t* g, bf16_t* l) {
    __builtin_amdgcn_global_load_lds((g_void*)g, (lds_void*)l, 16, 0, 0);
}

__device__ __forceinline__ void unpack4(uint2 r, float* o) {
    o[0] = __uint_as_float((r.x & 0xffffu) << 16); o[1] = __uint_as_float(r.x & 0xffff0000u);
    o[2] = __uint_as_float((r.y & 0xffffu) << 16); o[3] = __uint_as_float(r.y & 0xffff0000u);
}

// ---------------- weight fp32 -> bf16 conversion --------------------------------------
__global__ void cvt_weights(const float* __restrict__ sqkvw, const float* __restrict__ sow,
                            const float* __restrict__ sl1w,  const float* __restrict__ sl2w,
                            const float* __restrict__ tqkvw, const float* __restrict__ tow,
                            const float* __restrict__ tl1w,  const float* __restrict__ tl2w,
                            bf16_t* __restrict__ dst) {
    int i = blockIdx.x * 256 + threadIdx.x;  // total 1310720
    float v;
    if      (i <  393216) v = sqkvw[i];
    else if (i <  524288) v = sow  [i -  393216];
    else if (i <  589824) v = sl1w [i -  524288];
    else if (i <  655360) v = sl2w [i -  589824];
    else if (i < 1048576) v = tqkvw[i -  655360];
    else if (i < 1179648) v = tow  [i - 1048576];
    else if (i < 1245184) v = tl1w [i - 1179648];
    else                  v = tl2w [i - 1245184];
    dst[i] = (bf16_t)v;
}

// ---------------- embed: gelu(moveinfo @ w_in^T + b_in), cls=1e-5, layout [BC,9,256] ----
__global__ void embed_k(const float* __restrict__ mv, const float* __restrict__ w_in,
                        const float* __restrict__ b_in, bf16_t* __restrict__ x, int b0) {
    int blk = blockIdx.x; int d = threadIdx.x;
    int tok = blk % 9; int lb = blk / 9;
    size_t oidx = (size_t)blk * 256 + d;
    if (tok == 0) { x[oidx] = (bf16_t)1e-5f; return; }
    int bb = b0 + lb; int t = bb >> 8; int s = bb & 255;   // b = t*256+s
    int n = s * 8 + (tok - 1);
    float m0 = mv[((size_t)n * 64 + t) * 2];
    float m1 = mv[((size_t)n * 64 + t) * 2 + 1];
    float v = m0 * w_in[2 * d] + m1 * w_in[2 * d + 1] + b_in[d];
    v = 0.5f * v * (1.0f + erff(v * 0.70710678118654752f));  // exact gelu
    x[oidx] = (bf16_t)v;
}

// ---------------- plain GEMM: C = A @ W^T + bias (opt relu), bf16 out ------------------
// R2-exact version (measured 63.6-65 us): dual K-slab per barrier round (BK=64),
// 1-D grid XCD-grouped, swapped MFMA operands.
__global__ __launch_bounds__(256) void gemm_bt(const bf16_t* __restrict__ A,
                                               const bf16_t* __restrict__ W,
                                               const float* __restrict__ bias,
                                               bf16_t* __restrict__ C,
                                               int M, int N, int K, int relu) {
    __shared__ __align__(16) bf16_t As[8192];  // 2 slabs of [128][32]
    __shared__ __align__(16) bf16_t Ws[8192];
    int MT = M >> 7, NT = N >> 7;
    int g = blockIdx.x;
    int m_t, n_t;
    if ((MT & 7) == 0) {
        int x = g & 7, q = g >> 3;
        m_t = (q / NT) * 8 + x;
        n_t = q % NT;
    } else {
        m_t = g / NT; n_t = g % NT;
    }
    int tid = threadIdx.x;
    int lane = tid & 63;
    int wave = tid >> 6;
    int m0 = m_t * 128;
    int n0 = n_t * 128;
    int wm = (wave & 1) * 64;
    int wn = (wave >> 1) * 64;
    int arow = tid >> 2;
    int acol = (tid & 3) * 8;
    int fm = lane & 15;
    int fq = lane >> 4;

    floatx4 acc[4][4] = {};

    const bf16_t* Ag = A + (size_t)(m0 + arow) * K + acol;
    const bf16_t* Wg = W + (size_t)(n0 + arow) * K + acol;

    for (int k0 = 0; k0 < K; k0 += 64) {
        __syncthreads();
        ldg_lds16(Ag + k0,                       &As[tid * 8]);
        ldg_lds16(Ag + k0 + (size_t)64 * K,      &As[2048 + tid * 8]);
        ldg_lds16(Ag + k0 + 32,                  &As[4096 + tid * 8]);
        ldg_lds16(Ag + k0 + 32 + (size_t)64 * K, &As[6144 + tid * 8]);
        ldg_lds16(Wg + k0,                       &Ws[tid * 8]);
        ldg_lds16(Wg + k0 + (size_t)64 * K,      &Ws[2048 + tid * 8]);
        ldg_lds16(Wg + k0 + 32,                  &Ws[4096 + tid * 8]);
        ldg_lds16(Wg + k0 + 32 + (size_t)64 * K, &Ws[6144 + tid * 8]);
        __syncthreads();

#pragma unroll
        for (int sl = 0; sl < 2; sl++) {
            int base = sl * 4096;
            bf16x8 af[4], wf[4];
#pragma unroll
            for (int mi = 0; mi < 4; mi++)
                af[mi] = *(const bf16x8*)&As[base + (wm + mi * 16 + fm) * 32 + fq * 8];
#pragma unroll
            for (int ni = 0; ni < 4; ni++)
                wf[ni] = *(const bf16x8*)&Ws[base + (wn + ni * 16 + fm) * 32 + fq * 8];
#pragma unroll
            for (int mi = 0; mi < 4; mi++)
#pragma unroll
                for (int ni = 0; ni < 4; ni++)
                    acc[mi][ni] = __builtin_amdgcn_mfma_f32_16x16x32_bf16(wf[ni], af[mi], acc[mi][ni], 0, 0, 0);
        }
    }

#pragma unroll
    for (int mi = 0; mi < 4; mi++) {
        int row = m0 + wm + mi * 16 + fm;
#pragma unroll
        for (int ni = 0; ni < 4; ni++) {
            int colb = n0 + wn + ni * 16 + fq * 4;
            float4 b4 = *(const float4*)(bias + colb);
            float v0 = acc[mi][ni][0] + b4.x;
            float v1 = acc[mi][ni][1] + b4.y;
            float v2 = acc[mi][ni][2] + b4.z;
            float v3 = acc[mi][ni][3] + b4.w;
            if (relu) {
                v0 = fmaxf(v0, 0.f); v1 = fmaxf(v1, 0.f);
                v2 = fmaxf(v2, 0.f); v3 = fmaxf(v3, 0.f);
            }
            bf16_t t4[4] = {(bf16_t)v0, (bf16_t)v1, (bf16_t)v2, (bf16_t)v3};
            *(uint2*)(C + (size_t)row * N + colb) = *(uint2*)t4;
        }
    }
}

// ---------------- fused epilogue (BM=64): bias + residual + LN + store -----------------
// cls_bf/cls_f: optional extra store for rows%9==0 remapped to t_x layout (fuses cls_k).
__device__ __forceinline__ void epi_resln64(
    floatx4 (&acc)[4][4], int m0, int wn, int fm, int fq, int wave,
    const float* __restrict__ bias, const bf16_t* res_bf,
    const float* __restrict__ res_f, const float* __restrict__ lnw,
    const float* __restrict__ lnb, bf16_t* out_bf, float* out_f,
    bf16_t* cls_bf, float* cls_f, int b0,
    float (*rs)[64], float (*rss)[64]) {
    float s[4] = {0.f, 0.f, 0.f, 0.f}, ss[4] = {0.f, 0.f, 0.f, 0.f};
#pragma unroll
    for (int mi = 0; mi < 4; mi++) {
        size_t row = (size_t)(m0 + mi * 16 + fm);
#pragma unroll
        for (int ni = 0; ni < 4; ni++) {
            int col = wn + ni * 16 + fq * 4;
            float4 b4 = *(const float4*)(bias + col);
            float r4[4];
            if (res_f) {
                float4 t = *(const float4*)(res_f + row * 256 + col);
                r4[0] = t.x; r4[1] = t.y; r4[2] = t.z; r4[3] = t.w;
            } else {
                unpack4(*(const uint2*)(res_bf + row * 256 + col), r4);
            }
            float v0 = acc[mi][ni][0] + b4.x + r4[0];
            float v1 = acc[mi][ni][1] + b4.y + r4[1];
            float v2 = acc[mi][ni][2] + b4.z + r4[2];
            float v3 = acc[mi][ni][3] + b4.w + r4[3];
            acc[mi][ni][0] = v0; acc[mi][ni][1] = v1;
            acc[mi][ni][2] = v2; acc[mi][ni][3] = v3;
            s[mi] += v0 + v1 + v2 + v3;
            ss[mi] += v0 * v0 + v1 * v1 + v2 * v2 + v3 * v3;
        }
    }
#pragma unroll
    for (int mi = 0; mi < 4; mi++) {
        s[mi]  += __shfl_xor(s[mi], 16);  s[mi]  += __shfl_xor(s[mi], 32);
        ss[mi] += __shfl_xor(ss[mi], 16); ss[mi] += __shfl_xor(ss[mi], 32);
    }
    if (fq == 0) {
#pragma unroll
        for (int mi = 0; mi < 4; mi++) {
            rs [wave][mi * 16 + fm] = s[mi];
            rss[wave][mi * 16 + fm] = ss[mi];
        }
    }
    __syncthreads();
#pragma unroll
    for (int mi = 0; mi < 4; mi++) {
        int lrow = mi * 16 + fm;
        int grow = m0 + lrow;
        size_t row = (size_t)grow;
        float mean = (rs[0][lrow] + rs[1][lrow] + rs[2][lrow] + rs[3][lrow]) * (1.f / 256.f);
        float var  = (rss[0][lrow] + rss[1][lrow] + rss[2][lrow] + rss[3][lrow]) * (1.f / 256.f)
                   - mean * mean;
        float inv = rsqrtf(var + 1e-5f);
        int is_cls = (cls_bf != nullptr) && (grow % 9 == 0);
        size_t di = 0;
        if (is_cls) {
            int bb = b0 + grow / 9;
            int tt = bb >> 8, sseg = bb & 255;
            di = ((size_t)(sseg * 64 + tt)) * 256;
        }
#pragma unroll
        for (int ni = 0; ni < 4; ni++) {
            int col = wn + ni * 16 + fq * 4;
            float4 w4 = *(const float4*)(lnw + col);
            float4 bl = *(const float4*)(lnb + col);
            float o0 = (acc[mi][ni][0] - mean) * inv * w4.x + bl.x;
            float o1 = (acc[mi][ni][1] - mean) * inv * w4.y + bl.y;
            float o2 = (acc[mi][ni][2] - mean) * inv * w4.z + bl.z;
            float o3 = (acc[mi][ni][3] - mean) * inv * w4.w + bl.w;
            if (out_bf) {
                bf16_t t4[4] = {(bf16_t)o0, (bf16_t)o1, (bf16_t)o2, (bf16_t)o3};
                *(uint2*)(out_bf + row * 256 + col) = *(uint2*)t4;
            }
            if (out_f) {
                float4 t; t.x = o0; t.y = o1; t.z = o2; t.w = o3;
                *(float4*)(out_f + row * 256 + col) = t;
            }
            if (is_cls) {
                bf16_t t4[4] = {(bf16_t)o0, (bf16_t)o1, (bf16_t)o2, (bf16_t)o3};
                *(uint2*)(cls_bf + di + col) = *(uint2*)t4;
                float4 t; t.x = o0; t.y = o1; t.z = o2; t.w = o3;
                *(float4*)(cls_f + di + col) = t;
            }
        }
    }
}

// ---------------- fused proj GEMM (N=256,K=256) + residual + LN, BM=64 -----------------
// A has row-stride lda (768 when reading attn output aliased into the qkv q-region).
__global__ __launch_bounds__(256) void gemm_proj_ln(const bf16_t* __restrict__ A, int lda,
                                                    const bf16_t* __restrict__ W,
                                                    const float* __restrict__ bias,
                                                    const bf16_t* res_bf,
                                                    const float* __restrict__ res_f,
                                                    const float* __restrict__ lnw,
                                                    const float* __restrict__ lnb,
                                                    bf16_t* out_bf,
                                                    float* out_f) {
    __shared__ __align__(16) bf16_t As[4096];    // 2 bufs [64][32]
    __shared__ __align__(16) bf16_t Ws[16384];   // 2 bufs [256][32]
    __shared__ float rs[4][64], rss[4][64];
    int tid = threadIdx.x;
    int lane = tid & 63, wave = tid >> 6;
    int m0 = blockIdx.x * 64;
    int wn = wave * 64;
    int fm = lane & 15, fq = lane >> 4;
    floatx4 acc[4][4] = {};
    const bf16_t* Ag = A + (size_t)(m0 + (tid >> 2)) * lda + (tid & 3) * 8;
    const bf16_t* Wg = W + (size_t)(tid >> 2) * 256 + (tid & 3) * 8;

    auto STAGE = [&](int r, int b) {
        int k = r * 32;
        ldg_lds16(Ag + k, &As[b * 2048 + tid * 8]);
#pragma unroll
        for (int j = 0; j < 4; j++)
            ldg_lds16(Wg + k + j * 16384, &Ws[b * 8192 + j * 2048 + tid * 8]);
    };
    auto COMPUTE = [&](int b) {
        bf16x8 af[4], wf[4];
#pragma unroll
        for (int mi = 0; mi < 4; mi++)
            af[mi] = *(const bf16x8*)&As[b * 2048 + (mi * 16 + fm) * 32 + fq * 8];
#pragma unroll
        for (int ni = 0; ni < 4; ni++)
            wf[ni] = *(const bf16x8*)&Ws[b * 8192 + (wn + ni * 16 + fm) * 32 + fq * 8];
#pragma unroll
        for (int mi = 0; mi < 4; mi++)
#pragma unroll
            for (int ni = 0; ni < 4; ni++)
                acc[mi][ni] = __builtin_amdgcn_mfma_f32_16x16x32_bf16(wf[ni], af[mi], acc[mi][ni], 0, 0, 0);
    };

    STAGE(0, 0);
    __syncthreads();
    for (int r = 0; r < 7; ++r) {
        STAGE(r + 1, (r + 1) & 1);
        COMPUTE(r & 1);
        __syncthreads();
    }
    COMPUTE(1);
    epi_resln64(acc, m0, wn, fm, fq, wave, bias, res_bf, res_f, lnw, lnb,
                out_bf, out_f, nullptr, nullptr, 0, rs, rss);
}

// ---------------- fused FFN (BM=64): relu(X@w1^T+b1)@w2^T+b2 + residual + LN -----------
// cls_bf/cls_f non-null (final stage-A layer): suppress xc write, emit only cls rows.
__global__ __launch_bounds__(256) void gemm_ffn_ln(const bf16_t* __restrict__ X,
                                                   const bf16_t* __restrict__ w1,
                                                   const float* __restrict__ b1,
                                                   const bf16_t* __restrict__ w2,
                                                   const float* __restrict__ b2,
                                                   const float* __restrict__ lnw,
                                                   const float* __restrict__ lnb,
                                                   const float* __restrict__ res_f,
                                                   bf16_t* out_bf, float* out_f,
                                                   bf16_t* cls_bf, float* cls_f, int b0) {
    __shared__ __align__(16) bf16_t As[4096];    // 2 bufs [64][32]
    __shared__ __align__(16) bf16_t Ws[8192];    // w1: 2 bufs [128][32]
    __shared__ __align__(16) bf16_t Hs[10240];   // 4 k-slabs [64][40]
    __shared__ float rs[4][64], rss[4][64];
    int tid = threadIdx.x, lane = tid & 63, wave = tid >> 6;
    int m0 = blockIdx.x * 64;
    int wn1 = wave * 32;
    int wn2 = wave * 64;
    int fm = lane & 15, fq = lane >> 4;
    floatx4 acc[4][2] = {};
    const bf16_t* Ag = X + (size_t)(m0 + (tid >> 2)) * 256 + (tid & 3) * 8;
    const bf16_t* Wg = w1 + (size_t)(tid >> 2) * 256 + (tid & 3) * 8;

    auto STAGE = [&](int r, int b) {
        int k = r * 32;
        ldg_lds16(Ag + k, &As[b * 2048 + tid * 8]);
#pragma unroll
        for (int j = 0; j < 2; j++)
            ldg_lds16(Wg + k + j * 16384, &Ws[b * 4096 + j * 2048 + tid * 8]);
    };
    auto COMPUTE = [&](int b) {
        bf16x8 af[4], wf[2];
#pragma unroll
        for (int mi = 0; mi < 4; mi++)
            af[mi] = *(const bf16x8*)&As[b * 2048 + (mi * 16 + fm) * 32 + fq * 8];
#pragma unroll
        for (int ni = 0; ni < 2; ni++)
            wf[ni] = *(const bf16x8*)&Ws[b * 4096 + (wn1 + ni * 16 + fm) * 32 + fq * 8];
#pragma unroll
        for (int mi = 0; mi < 4; mi++)
#pragma unroll
            for (int ni = 0; ni < 2; ni++)
                acc[mi][ni] = __builtin_amdgcn_mfma_f32_16x16x32_bf16(wf[ni], af[mi], acc[mi][ni], 0, 0, 0);
    };

    STAGE(0, 0);
    __syncthreads();
    for (int r = 0; r < 7; ++r) {
        STAGE(r + 1, (r + 1) & 1);
        COMPUTE(r & 1);
        __syncthreads();
    }
    COMPUTE(1);

    // h = relu(acc + b1) -> Hs (k-slab layout [ks][64][40] matching phase-2 reads)
#pragma unroll
    for (int mi = 0; mi < 4; mi++) {
        int row = mi * 16 + fm;
#pragma unroll
        for (int ni = 0; ni < 2; ni++) {
            int c = wn1 + ni * 16 + fq * 4;
            float4 b4 = *(const float4*)(b1 + c);
            bf16_t t4[4];
            t4[0] = (bf16_t)fmaxf(acc[mi][ni][0] + b4.x, 0.f);
            t4[1] = (bf16_t)fmaxf(acc[mi][ni][1] + b4.y, 0.f);
            t4[2] = (bf16_t)fmaxf(acc[mi][ni][2] + b4.z, 0.f);
            t4[3] = (bf16_t)fmaxf(acc[mi][ni][3] + b4.w, 0.f);
            *(uint2*)&Hs[(c >> 5) * 2560 + row * 40 + (c & 31)] = *(uint2*)t4;
        }
    }
    __syncthreads();
    floatx4 acc2[4][4] = {};
#pragma unroll
    for (int ks = 0; ks < 4; ks++) {
        bf16x8 af2[4];
#pragma unroll
        for (int mi = 0; mi < 4; mi++)
            af2[mi] = *(const bf16x8*)&Hs[ks * 2560 + (mi * 16 + fm) * 40 + fq * 8];
#pragma unroll
        for (int ni = 0; ni < 4; ni++) {
            bf16x8 wf2 = *(const bf16x8*)(w2 + (size_t)(wn2 + ni * 16 + fm) * 128 + ks * 32 + fq * 8);
#pragma unroll
            for (int mi = 0; mi < 4; mi++)
                acc2[mi][ni] = __builtin_amdgcn_mfma_f32_16x16x32_bf16(wf2, af2[mi], acc2[mi][ni], 0, 0, 0);
        }
    }
    epi_resln64(acc2, m0, wn2, fm, fq, wave, b2, X, res_f, lnw, lnb,
                out_bf, out_f, cls_bf, cls_f, b0, rs, rss);
}

// ---------------- attention, seqlen 9: 4 seqs / 320-thread block -----------------------
// K,V-only LDS; q direct from global. ao ALIASES the qkv q-region (stride 768): item
// (s,h,i) reads q[row,hseg] then writes ao to the same bytes — same-thread RAW, and all
// other threads touch disjoint (row,hseg). No __restrict__ on qkv/ao (they alias).
__global__ __launch_bounds__(320) void attn9_k(const bf16_t* qkv, bf16_t* ao) {
    __shared__ __align__(16) bf16_t kv[36 * 512];  // [s*9+j][ k(256) | v(256) ]
    int b = blockIdx.x; int tid = threadIdx.x;
    const bf16_t* src = qkv + (size_t)b * 27648;   // 36 rows x 768
    for (int c = tid; c < 2304; c += 320) {        // 36 rows x 64 chunks of 16B
        int row = c >> 6; int off = (c & 63) << 3;
        *(uint4*)&kv[row * 512 + off] = *(const uint4*)&src[row * 768 + 256 + off];
    }
    __syncthreads();
    if (tid < 288) {
        int s = tid / 72; int rem = tid - s * 72; int h = rem / 9; int i = rem - h * 9;
        const bf16_t* qp = src + (size_t)(s * 9 + i) * 768 + h * 32;
        float qf[32];
#pragma unroll
        for (int c = 0; c < 4; c++) {
            bf16x8 t8 = *(const bf16x8*)(qp + c * 8);
#pragma unroll
            for (int e = 0; e < 8; e++) qf[c * 8 + e] = (float)t8[e];
        }
        float sc[9]; float mx = -1e30f;
#pragma unroll
        for (int j = 0; j < 9; j++) {
            const bf16_t* kp = &kv[(s * 9 + j) * 512 + h * 32];
            float d = 0.f;
#pragma unroll
            for (int c = 0; c < 4; c++) {
                bf16x8 t8 = *(const bf16x8*)(kp + c * 8);
#pragma unroll
                for (int e = 0; e < 8; e++) d += qf[c * 8 + e] * (float)t8[e];
            }
            d *= 0.17677669529663687f;
            sc[j] = d; mx = fmaxf(mx, d);
        }
        float den = 0.f;
#pragma unroll
        for (int j = 0; j < 9; j++) { sc[j] = __expf(sc[j] - mx); den += sc[j]; }
        float inv = 1.0f / den;
        float of[32] = {};
#pragma unroll
        for (int j = 0; j < 9; j++) {
            const bf16_t* vp = &kv[(s * 9 + j) * 512 + 256 + h * 32];
            float w = sc[j];
#pragma unroll
            for (int c = 0; c < 4; c++) {
                bf16x8 t8 = *(const bf16x8*)(vp + c * 8);
#pragma unroll
                for (int e = 0; e < 8; e++) of[c * 8 + e] += w * (float)t8[e];
            }
        }
        bf16_t* dst = ao + ((size_t)(b * 36 + s * 9 + i)) * 768 + h * 32;  // q-region, stride 768
#pragma unroll
        for (int c = 0; c < 4; c++) {
            bf16x8 o8;
#pragma unroll
            for (int e = 0; e < 8; e++) o8[e] = (bf16_t)(of[c * 8 + e] * inv);
            *(bf16x8*)(dst + c * 8) = o8;
        }
    }
}

// ---------------- attention, seqlen 64 (stage C) ---------------------------------------
// ao aliases tqkv q-region (stride 768): q reads complete before barrier 1, ao writes
// after barrier 3 -> ordered. No __restrict__.
__global__ __launch_bounds__(256) void attn64_k(const bf16_t* qkv, bf16_t* ao) {
    __shared__ __align__(16) float kk[64 * 36];   // padded rows
    __shared__ __align__(16) float vv[64 * 36];
    __shared__ __align__(16) float pp[64 * 64];   // P[j][i]
    __shared__ float mloc[4 * 64];
    __shared__ float sloc[4 * 64];
    int s = blockIdx.x >> 3, h = blockIdx.x & 7;
    int t = threadIdx.x;
    int i = t & 63;
    int wq = t >> 6;

    {
        int r = t >> 2, c = t & 3;
        const bf16_t* kb = qkv + ((size_t)(s * 64 + r)) * 768 + h * 32 + 256 + c * 8;
        bf16x8 k8 = *(const bf16x8*)kb;
        bf16x8 v8 = *(const bf16x8*)(kb + 256);
        float* kd = &kk[r * 36 + c * 8];
        float* vd = &vv[r * 36 + c * 8];
#pragma unroll
        for (int e = 0; e < 8; e++) { kd[e] = (float)k8[e]; vd[e] = (float)v8[e]; }
    }
    const bf16_t* qb = qkv + ((size_t)(s * 64 + i)) * 768 + h * 32;
    float qf[32];
#pragma unroll
    for (int c = 0; c < 4; c++) {
        bf16x8 t8 = *(const bf16x8*)(qb + c * 8);
#pragma unroll
        for (int e = 0; e < 8; e++) qf[c * 8 + e] = (float)t8[e];
    }
    __syncthreads();

    float sc[16]; float mx = -1e30f;
#pragma unroll
    for (int jj = 0; jj < 16; jj++) {
        int j = wq * 16 + jj;
        const float* kr = &kk[j * 36];
        float d = 0.f;
#pragma unroll
        for (int c = 0; c < 8; c++) {
            float4 k4 = *(const float4*)(kr + c * 4);
            d += qf[c*4+0]*k4.x + qf[c*4+1]*k4.y + qf[c*4+2]*k4.z + qf[c*4+3]*k4.w;
        }
        d *= 0.17677669529663687f;
        sc[jj] = d; mx = fmaxf(mx, d);
    }
    float se = 0.f;
#pragma unroll
    for (int jj = 0; jj < 16; jj++) se += __expf(sc[jj] - mx);
    mloc[wq * 64 + i] = mx;
    sloc[wq * 64 + i] = se;
    __syncthreads();

    float m0 = mloc[i], m1 = mloc[64 + i], m2 = mloc[128 + i], m3 = mloc[192 + i];
    float gm = fmaxf(fmaxf(m0, m1), fmaxf(m2, m3));
    float D = sloc[i] * __expf(m0 - gm) + sloc[64 + i] * __expf(m1 - gm)
            + sloc[128 + i] * __expf(m2 - gm) + sloc[192 + i] * __expf(m3 - gm);

#pragma unroll
    for (int jj = 0; jj < 16; jj++)
        pp[(wq * 16 + jj) * 64 + i] = __expf(sc[jj] - gm);
    __syncthreads();

    float of[8] = {};
    for (int j = 0; j < 64; j++) {
        float w = pp[j * 64 + i];
        const float* vr = &vv[j * 36 + wq * 8];
        float4 va = *(const float4*)vr;
        float4 vb = *(const float4*)(vr + 4);
        of[0] += w * va.x; of[1] += w * va.y; of[2] += w * va.z; of[3] += w * va.w;
        of[4] += w * vb.x; of[5] += w * vb.y; of[6] += w * vb.z; of[7] += w * vb.w;
    }
    float invD = 1.0f / D;
    bf16_t o8[8];
#pragma unroll
    for (int e = 0; e < 8; e++) o8[e] = (bf16_t)(of[e] * invD);
    *(uint4*)(ao + ((size_t)(s * 64 + i)) * 768 + h * 32 + wq * 8) = *(uint4*)o8;  // q-region
}

// ------------------------------------------------------------------------------------------
extern "C" void kernel_launch(void* const* d_in, const int* in_sizes, int n_in,
                              void* d_out, int out_size, void* d_ws, size_t ws_size,
                              hipStream_t stream) {
    const float* mv   = (const float*)d_in[0];
    const float* w_in = (const float*)d_in[2];
    const float* b_in = (const float*)d_in[3];
    const float* sp[12]; const float* tp[12];
    for (int i = 0; i < 12; i++) { sp[i] = (const float*)d_in[4 + i]; tp[i] = (const float*)d_in[16 + i]; }
    // idx: 0 qkvw, 1 qkvb, 2 ow, 3 ob, 4 l1w, 5 l1b, 6 l2w, 7 l2b, 8 ln1w, 9 ln1b, 10 ln2w, 11 ln2b

    bf16_t* wbf = (bf16_t*)d_ws;              // 1310720 bf16 weights
    bf16_t* txb = wbf + 1310720;              // t_x bf16: 16384*256
    float*  txf = (float*)(txb + 4194304);    // t_x fp32: 16384*256
    bf16_t* pool = (bf16_t*)(txf + 4194304);

    long long headB = 2621440LL + 8388608LL + 16777216LL;  // wbf + txb + txf bytes
    long long cand[5] = {16384, 8192, 4096, 2048, 1024};
    int BC = 1024;
    for (int c = 0; c < 5; c++) {
        long long poolB = cand[c] * 9216LL * 2;             // x(2304) + qkv(6912); ao aliases q
        if (poolB < 25165824LL) poolB = 25165824LL;         // stage-C floor: tqkv
        if ((size_t)(headB + poolB) <= ws_size) { BC = (int)cand[c]; break; }
    }

    cvt_weights<<<5120, 256, 0, stream>>>(sp[0], sp[2], sp[4], sp[6], tp[0], tp[2], tp[4], tp[6], wbf);

    const int M = BC * 9;
    const int MT64 = M / 64;
    bf16_t* xc    = pool;
    bf16_t* qkvb_ = pool + (long long)BC * 2304;

    for (int b0 = 0; b0 < 16384; b0 += BC) {
        embed_k<<<dim3(M), 256, 0, stream>>>(mv, w_in, b_in, xc, b0);
        for (int l = 0; l < 2; l++) {
            const bf16_t* wq = wbf + 0      + l * 196608;
            const bf16_t* wo = wbf + 393216 + l * 65536;
            const bf16_t* w1 = wbf + 524288 + l * 32768;
            const bf16_t* w2 = wbf + 589824 + l * 32768;
            gemm_bt<<<dim3((M / 128) * 6), 256, 0, stream>>>(xc, wq, sp[1] + l * 768, qkvb_, M, 768, 256, 0);
            attn9_k<<<dim3(BC / 4), 320, 0, stream>>>(qkvb_, qkvb_);
            gemm_proj_ln<<<dim3(MT64), 256, 0, stream>>>(qkvb_, 768, wo, sp[3] + l * 256,
                                                         xc, (const float*)nullptr,
                                                         sp[8] + l * 256, sp[9] + l * 256,
                                                         xc, (float*)nullptr);
            if (l == 0)
                gemm_ffn_ln<<<dim3(MT64), 256, 0, stream>>>(xc, w1, sp[5] + l * 128,
                                                            w2, sp[7] + l * 256,
                                                            sp[10] + l * 256, sp[11] + l * 256,
                                                            (const float*)nullptr,
                                                            xc, (float*)nullptr,
                                                            (bf16_t*)nullptr, (float*)nullptr, 0);
            else
                gemm_ffn_ln<<<dim3(MT64), 256, 0, stream>>>(xc, w1, sp[5] + l * 128,
                                                            w2, sp[7] + l * 256,
                                                            sp[10] + l * 256, sp[11] + l * 256,
                                                            (const float*)nullptr,
                                                            (bf16_t*)nullptr, (float*)nullptr,
                                                            txb, txf, b0);
        }
    }

    // ---- stage C: 256 seqs x 64 tokens, fp32 residual sidecar ----
    bf16_t* tqkv = pool;                    // 16384*768; attn output aliases q-region
    for (int l = 0; l < 2; l++) {
        gemm_bt<<<dim3(128 * 6), 256, 0, stream>>>(txb, wbf + 655360 + l * 196608, tp[1] + l * 768,
                                                   tqkv, 16384, 768, 256, 0);
        attn64_k<<<dim3(2048), 256, 0, stream>>>(tqkv, tqkv);
        gemm_proj_ln<<<dim3(256), 256, 0, stream>>>(tqkv, 768, wbf + 1048576 + l * 65536, tp[3] + l * 256,
                                                    (const bf16_t*)nullptr, txf,
                                                    tp[8] + l * 256, tp[9] + l * 256,
                                                    txb, txf);
        gemm_ffn_ln<<<dim3(256), 256, 0, stream>>>(txb, wbf + 1179648 + l * 32768, tp[5] + l * 128,
                                                   wbf + 1245184 + l * 32768, tp[7] + l * 256,
                                                   tp[10] + l * 256, tp[11] + l * 256,
                                                   txf,
                                                   (l == 0) ? txb : (bf16_t*)nullptr,
                                                   (l == 0) ? txf : (float*)d_out,
                                                   (bf16_t*)nullptr, (float*)nullptr, 0);
    }
}

// Round 10
// 1056.632 us; speedup vs baseline: 1.0380x; 1.0380x over previous
//
#include <hip/hip_runtime.h>
#include <hip/hip_bf16.h>
#include <math.h>

typedef __bf16 bf16_t;
typedef float floatx4 __attribute__((ext_vector_type(4)));
typedef bf16_t bf16x8 __attribute__((ext_vector_type(8)));

typedef __attribute__((address_space(1))) void g_void;
typedef __attribute__((address_space(3))) void lds_void;

__device__ __forceinline__ void ldg_lds16(const bf16_t* g, bf16_t* l) {
    __builtin_amdgcn_global_load_lds((g_void*)g, (lds_void*)l, 16, 0, 0);
}

__device__ __forceinline__ void unpack4(uint2 r, float* o) {
    o[0] = __uint_as_float((r.x & 0xffffu) << 16); o[1] = __uint_as_float(r.x & 0xffff0000u);
    o[2] = __uint_as_float((r.y & 0xffffu) << 16); o[3] = __uint_as_float(r.y & 0xffff0000u);
}

// ---------------- weight fp32 -> bf16 conversion --------------------------------------
__global__ void cvt_weights(const float* __restrict__ sqkvw, const float* __restrict__ sow,
                            const float* __restrict__ sl1w,  const float* __restrict__ sl2w,
                            const float* __restrict__ tqkvw, const float* __restrict__ tow,
                            const float* __restrict__ tl1w,  const float* __restrict__ tl2w,
                            bf16_t* __restrict__ dst) {
    int i = blockIdx.x * 256 + threadIdx.x;  // total 1310720
    float v;
    if      (i <  393216) v = sqkvw[i];
    else if (i <  524288) v = sow  [i -  393216];
    else if (i <  589824) v = sl1w [i -  524288];
    else if (i <  655360) v = sl2w [i -  589824];
    else if (i < 1048576) v = tqkvw[i -  655360];
    else if (i < 1179648) v = tow  [i - 1048576];
    else if (i < 1245184) v = tl1w [i - 1179648];
    else                  v = tl2w [i - 1245184];
    dst[i] = (bf16_t)v;
}

// ---------------- embed: gelu(moveinfo @ w_in^T + b_in), cls=1e-5, layout [BC,9,256] ----
__global__ void embed_k(const float* __restrict__ mv, const float* __restrict__ w_in,
                        const float* __restrict__ b_in, bf16_t* __restrict__ x, int b0) {
    int blk = blockIdx.x; int d = threadIdx.x;
    int tok = blk % 9; int lb = blk / 9;
    size_t oidx = (size_t)blk * 256 + d;
    if (tok == 0) { x[oidx] = (bf16_t)1e-5f; return; }
    int bb = b0 + lb; int t = bb >> 8; int s = bb & 255;   // b = t*256+s
    int n = s * 8 + (tok - 1);
    float m0 = mv[((size_t)n * 64 + t) * 2];
    float m1 = mv[((size_t)n * 64 + t) * 2 + 1];
    float v = m0 * w_in[2 * d] + m1 * w_in[2 * d + 1] + b_in[d];
    v = 0.5f * v * (1.0f + erff(v * 0.70710678118654752f));  // exact gelu
    x[oidx] = (bf16_t)v;
}

// ---------------- plain GEMM: C = A @ W^T + bias (opt relu), bf16 out ------------------
// R2-exact version (measured 62.6-65 us): dual K-slab per barrier round (BK=64),
// 1-D grid XCD-grouped, swapped MFMA operands.
__global__ __launch_bounds__(256) void gemm_bt(const bf16_t* __restrict__ A,
                                               const bf16_t* __restrict__ W,
                                               const float* __restrict__ bias,
                                               bf16_t* __restrict__ C,
                                               int M, int N, int K, int relu) {
    __shared__ __align__(16) bf16_t As[8192];  // 2 slabs of [128][32]
    __shared__ __align__(16) bf16_t Ws[8192];
    int MT = M >> 7, NT = N >> 7;
    int g = blockIdx.x;
    int m_t, n_t;
    if ((MT & 7) == 0) {
        int x = g & 7, q = g >> 3;
        m_t = (q / NT) * 8 + x;
        n_t = q % NT;
    } else {
        m_t = g / NT; n_t = g % NT;
    }
    int tid = threadIdx.x;
    int lane = tid & 63;
    int wave = tid >> 6;
    int m0 = m_t * 128;
    int n0 = n_t * 128;
    int wm = (wave & 1) * 64;
    int wn = (wave >> 1) * 64;
    int arow = tid >> 2;
    int acol = (tid & 3) * 8;
    int fm = lane & 15;
    int fq = lane >> 4;

    floatx4 acc[4][4] = {};

    const bf16_t* Ag = A + (size_t)(m0 + arow) * K + acol;
    const bf16_t* Wg = W + (size_t)(n0 + arow) * K + acol;

    for (int k0 = 0; k0 < K; k0 += 64) {
        __syncthreads();
        ldg_lds16(Ag + k0,                       &As[tid * 8]);
        ldg_lds16(Ag + k0 + (size_t)64 * K,      &As[2048 + tid * 8]);
        ldg_lds16(Ag + k0 + 32,                  &As[4096 + tid * 8]);
        ldg_lds16(Ag + k0 + 32 + (size_t)64 * K, &As[6144 + tid * 8]);
        ldg_lds16(Wg + k0,                       &Ws[tid * 8]);
        ldg_lds16(Wg + k0 + (size_t)64 * K,      &Ws[2048 + tid * 8]);
        ldg_lds16(Wg + k0 + 32,                  &Ws[4096 + tid * 8]);
        ldg_lds16(Wg + k0 + 32 + (size_t)64 * K, &Ws[6144 + tid * 8]);
        __syncthreads();

#pragma unroll
        for (int sl = 0; sl < 2; sl++) {
            int base = sl * 4096;
            bf16x8 af[4], wf[4];
#pragma unroll
            for (int mi = 0; mi < 4; mi++)
                af[mi] = *(const bf16x8*)&As[base + (wm + mi * 16 + fm) * 32 + fq * 8];
#pragma unroll
            for (int ni = 0; ni < 4; ni++)
                wf[ni] = *(const bf16x8*)&Ws[base + (wn + ni * 16 + fm) * 32 + fq * 8];
#pragma unroll
            for (int mi = 0; mi < 4; mi++)
#pragma unroll
                for (int ni = 0; ni < 4; ni++)
                    acc[mi][ni] = __builtin_amdgcn_mfma_f32_16x16x32_bf16(wf[ni], af[mi], acc[mi][ni], 0, 0, 0);
        }
    }

#pragma unroll
    for (int mi = 0; mi < 4; mi++) {
        int row = m0 + wm + mi * 16 + fm;
#pragma unroll
        for (int ni = 0; ni < 4; ni++) {
            int colb = n0 + wn + ni * 16 + fq * 4;
            float4 b4 = *(const float4*)(bias + colb);
            float v0 = acc[mi][ni][0] + b4.x;
            float v1 = acc[mi][ni][1] + b4.y;
            float v2 = acc[mi][ni][2] + b4.z;
            float v3 = acc[mi][ni][3] + b4.w;
            if (relu) {
                v0 = fmaxf(v0, 0.f); v1 = fmaxf(v1, 0.f);
                v2 = fmaxf(v2, 0.f); v3 = fmaxf(v3, 0.f);
            }
            bf16_t t4[4] = {(bf16_t)v0, (bf16_t)v1, (bf16_t)v2, (bf16_t)v3};
            *(uint2*)(C + (size_t)row * N + colb) = *(uint2*)t4;
        }
    }
}

// ---------------- fused epilogue (BM=64): bias + residual + LN + store -----------------
// cls_bf/cls_f: optional extra store for rows%9==0 remapped to t_x layout (fuses cls_k).
__device__ __forceinline__ void epi_resln64(
    floatx4 (&acc)[4][4], int m0, int wn, int fm, int fq, int wave,
    const float* __restrict__ bias, const bf16_t* __restrict__ res_bf,
    const float* __restrict__ res_f, const float* __restrict__ lnw,
    const float* __restrict__ lnb, bf16_t* out_bf, float* out_f,
    bf16_t* cls_bf, float* cls_f, int b0,
    float (*rs)[64], float (*rss)[64]) {
    float s[4] = {0.f, 0.f, 0.f, 0.f}, ss[4] = {0.f, 0.f, 0.f, 0.f};
#pragma unroll
    for (int mi = 0; mi < 4; mi++) {
        size_t row = (size_t)(m0 + mi * 16 + fm);
#pragma unroll
        for (int ni = 0; ni < 4; ni++) {
            int col = wn + ni * 16 + fq * 4;
            float4 b4 = *(const float4*)(bias + col);
            float r4[4];
            if (res_f) {
                float4 t = *(const float4*)(res_f + row * 256 + col);
                r4[0] = t.x; r4[1] = t.y; r4[2] = t.z; r4[3] = t.w;
            } else {
                unpack4(*(const uint2*)(res_bf + row * 256 + col), r4);
            }
            float v0 = acc[mi][ni][0] + b4.x + r4[0];
            float v1 = acc[mi][ni][1] + b4.y + r4[1];
            float v2 = acc[mi][ni][2] + b4.z + r4[2];
            float v3 = acc[mi][ni][3] + b4.w + r4[3];
            acc[mi][ni][0] = v0; acc[mi][ni][1] = v1;
            acc[mi][ni][2] = v2; acc[mi][ni][3] = v3;
            s[mi] += v0 + v1 + v2 + v3;
            ss[mi] += v0 * v0 + v1 * v1 + v2 * v2 + v3 * v3;
        }
    }
#pragma unroll
    for (int mi = 0; mi < 4; mi++) {
        s[mi]  += __shfl_xor(s[mi], 16);  s[mi]  += __shfl_xor(s[mi], 32);
        ss[mi] += __shfl_xor(ss[mi], 16); ss[mi] += __shfl_xor(ss[mi], 32);
    }
    if (fq == 0) {
#pragma unroll
        for (int mi = 0; mi < 4; mi++) {
            rs [wave][mi * 16 + fm] = s[mi];
            rss[wave][mi * 16 + fm] = ss[mi];
        }
    }
    __syncthreads();
#pragma unroll
    for (int mi = 0; mi < 4; mi++) {
        int lrow = mi * 16 + fm;
        int grow = m0 + lrow;
        size_t row = (size_t)grow;
        float mean = (rs[0][lrow] + rs[1][lrow] + rs[2][lrow] + rs[3][lrow]) * (1.f / 256.f);
        float var  = (rss[0][lrow] + rss[1][lrow] + rss[2][lrow] + rss[3][lrow]) * (1.f / 256.f)
                   - mean * mean;
        float inv = rsqrtf(var + 1e-5f);
        int is_cls = (cls_bf != nullptr) && (grow % 9 == 0);
        size_t di = 0;
        if (is_cls) {
            int bb = b0 + grow / 9;
            int tt = bb >> 8, sseg = bb & 255;
            di = ((size_t)(sseg * 64 + tt)) * 256;
        }
#pragma unroll
        for (int ni = 0; ni < 4; ni++) {
            int col = wn + ni * 16 + fq * 4;
            float4 w4 = *(const float4*)(lnw + col);
            float4 bl = *(const float4*)(lnb + col);
            float o0 = (acc[mi][ni][0] - mean) * inv * w4.x + bl.x;
            float o1 = (acc[mi][ni][1] - mean) * inv * w4.y + bl.y;
            float o2 = (acc[mi][ni][2] - mean) * inv * w4.z + bl.z;
            float o3 = (acc[mi][ni][3] - mean) * inv * w4.w + bl.w;
            if (out_bf) {
                bf16_t t4[4] = {(bf16_t)o0, (bf16_t)o1, (bf16_t)o2, (bf16_t)o3};
                *(uint2*)(out_bf + row * 256 + col) = *(uint2*)t4;
            }
            if (out_f) {
                float4 t; t.x = o0; t.y = o1; t.z = o2; t.w = o3;
                *(float4*)(out_f + row * 256 + col) = t;
            }
            if (is_cls) {
                bf16_t t4[4] = {(bf16_t)o0, (bf16_t)o1, (bf16_t)o2, (bf16_t)o3};
                *(uint2*)(cls_bf + di + col) = *(uint2*)t4;
                float4 t; t.x = o0; t.y = o1; t.z = o2; t.w = o3;
                *(float4*)(cls_f + di + col) = t;
            }
        }
    }
}

// ---------------- fused proj GEMM (N=256,K=256) + residual + LN, BM=64 -----------------
// R5/R8 version: 2-phase pipelined BK=32 K-loop, dense A (stride 256).
__global__ __launch_bounds__(256) void gemm_proj_ln(const bf16_t* __restrict__ A,
                                                    const bf16_t* __restrict__ W,
                                                    const float* __restrict__ bias,
                                                    const bf16_t* __restrict__ res_bf,
                                                    const float* __restrict__ res_f,
                                                    const float* __restrict__ lnw,
                                                    const float* __restrict__ lnb,
                                                    bf16_t* out_bf,
                                                    float* out_f) {
    __shared__ __align__(16) bf16_t As[4096];    // 2 bufs [64][32]
    __shared__ __align__(16) bf16_t Ws[16384];   // 2 bufs [256][32]
    __shared__ float rs[4][64], rss[4][64];
    int tid = threadIdx.x;
    int lane = tid & 63, wave = tid >> 6;
    int m0 = blockIdx.x * 64;
    int wn = wave * 64;
    int fm = lane & 15, fq = lane >> 4;
    floatx4 acc[4][4] = {};
    const bf16_t* Ag = A + (size_t)(m0 + (tid >> 2)) * 256 + (tid & 3) * 8;
    const bf16_t* Wg = W + (size_t)(tid >> 2) * 256 + (tid & 3) * 8;

    auto STAGE = [&](int r, int b) {
        int k = r * 32;
        ldg_lds16(Ag + k, &As[b * 2048 + tid * 8]);
#pragma unroll
        for (int j = 0; j < 4; j++)
            ldg_lds16(Wg + k + j * 16384, &Ws[b * 8192 + j * 2048 + tid * 8]);
    };
    auto COMPUTE = [&](int b) {
        bf16x8 af[4], wf[4];
#pragma unroll
        for (int mi = 0; mi < 4; mi++)
            af[mi] = *(const bf16x8*)&As[b * 2048 + (mi * 16 + fm) * 32 + fq * 8];
#pragma unroll
        for (int ni = 0; ni < 4; ni++)
            wf[ni] = *(const bf16x8*)&Ws[b * 8192 + (wn + ni * 16 + fm) * 32 + fq * 8];
#pragma unroll
        for (int mi = 0; mi < 4; mi++)
#pragma unroll
            for (int ni = 0; ni < 4; ni++)
                acc[mi][ni] = __builtin_amdgcn_mfma_f32_16x16x32_bf16(wf[ni], af[mi], acc[mi][ni], 0, 0, 0);
    };

    STAGE(0, 0);
    __syncthreads();
    for (int r = 0; r < 7; ++r) {
        STAGE(r + 1, (r + 1) & 1);
        COMPUTE(r & 1);
        __syncthreads();
    }
    COMPUTE(1);
    epi_resln64(acc, m0, wn, fm, fq, wave, bias, res_bf, res_f, lnw, lnb,
                out_bf, out_f, nullptr, nullptr, 0, rs, rss);
}

// ---------------- fused FFN (BM=64): relu(X@w1^T+b1)@w2^T+b2 + residual + LN -----------
// cls_bf/cls_f non-null (final stage-A layer): suppress xc write, emit only cls rows.
__global__ __launch_bounds__(256) void gemm_ffn_ln(const bf16_t* __restrict__ X,
                                                   const bf16_t* __restrict__ w1,
                                                   const float* __restrict__ b1,
                                                   const bf16_t* __restrict__ w2,
                                                   const float* __restrict__ b2,
                                                   const float* __restrict__ lnw,
                                                   const float* __restrict__ lnb,
                                                   const float* __restrict__ res_f,
                                                   bf16_t* out_bf, float* out_f,
                                                   bf16_t* cls_bf, float* cls_f, int b0) {
    __shared__ __align__(16) bf16_t As[4096];    // 2 bufs [64][32]
    __shared__ __align__(16) bf16_t Ws[8192];    // w1: 2 bufs [128][32]
    __shared__ __align__(16) bf16_t Hs[10240];   // 4 k-slabs [64][40]
    __shared__ float rs[4][64], rss[4][64];
    int tid = threadIdx.x, lane = tid & 63, wave = tid >> 6;
    int m0 = blockIdx.x * 64;
    int wn1 = wave * 32;
    int wn2 = wave * 64;
    int fm = lane & 15, fq = lane >> 4;
    floatx4 acc[4][2] = {};
    const bf16_t* Ag = X + (size_t)(m0 + (tid >> 2)) * 256 + (tid & 3) * 8;
    const bf16_t* Wg = w1 + (size_t)(tid >> 2) * 256 + (tid & 3) * 8;

    auto STAGE = [&](int r, int b) {
        int k = r * 32;
        ldg_lds16(Ag + k, &As[b * 2048 + tid * 8]);
#pragma unroll
        for (int j = 0; j < 2; j++)
            ldg_lds16(Wg + k + j * 16384, &Ws[b * 4096 + j * 2048 + tid * 8]);
    };
    auto COMPUTE = [&](int b) {
        bf16x8 af[4], wf[2];
#pragma unroll
        for (int mi = 0; mi < 4; mi++)
            af[mi] = *(const bf16x8*)&As[b * 2048 + (mi * 16 + fm) * 32 + fq * 8];
#pragma unroll
        for (int ni = 0; ni < 2; ni++)
            wf[ni] = *(const bf16x8*)&Ws[b * 4096 + (wn1 + ni * 16 + fm) * 32 + fq * 8];
#pragma unroll
        for (int mi = 0; mi < 4; mi++)
#pragma unroll
            for (int ni = 0; ni < 2; ni++)
                acc[mi][ni] = __builtin_amdgcn_mfma_f32_16x16x32_bf16(wf[ni], af[mi], acc[mi][ni], 0, 0, 0);
    };

    STAGE(0, 0);
    __syncthreads();
    for (int r = 0; r < 7; ++r) {
        STAGE(r + 1, (r + 1) & 1);
        COMPUTE(r & 1);
        __syncthreads();
    }
    COMPUTE(1);

    // h = relu(acc + b1) -> Hs (k-slab layout [ks][64][40] matching phase-2 reads)
#pragma unroll
    for (int mi = 0; mi < 4; mi++) {
        int row = mi * 16 + fm;
#pragma unroll
        for (int ni = 0; ni < 2; ni++) {
            int c = wn1 + ni * 16 + fq * 4;
            float4 b4 = *(const float4*)(b1 + c);
            bf16_t t4[4];
            t4[0] = (bf16_t)fmaxf(acc[mi][ni][0] + b4.x, 0.f);
            t4[1] = (bf16_t)fmaxf(acc[mi][ni][1] + b4.y, 0.f);
            t4[2] = (bf16_t)fmaxf(acc[mi][ni][2] + b4.z, 0.f);
            t4[3] = (bf16_t)fmaxf(acc[mi][ni][3] + b4.w, 0.f);
            *(uint2*)&Hs[(c >> 5) * 2560 + row * 40 + (c & 31)] = *(uint2*)t4;
        }
    }
    __syncthreads();
    floatx4 acc2[4][4] = {};
#pragma unroll
    for (int ks = 0; ks < 4; ks++) {
        bf16x8 af2[4];
#pragma unroll
        for (int mi = 0; mi < 4; mi++)
            af2[mi] = *(const bf16x8*)&Hs[ks * 2560 + (mi * 16 + fm) * 40 + fq * 8];
#pragma unroll
        for (int ni = 0; ni < 4; ni++) {
            bf16x8 wf2 = *(const bf16x8*)(w2 + (size_t)(wn2 + ni * 16 + fm) * 128 + ks * 32 + fq * 8);
#pragma unroll
            for (int mi = 0; mi < 4; mi++)
                acc2[mi][ni] = __builtin_amdgcn_mfma_f32_16x16x32_bf16(wf2, af2[mi], acc2[mi][ni], 0, 0, 0);
        }
    }
    epi_resln64(acc2, m0, wn2, fm, fq, wave, b2, X, res_f, lnw, lnb,
                out_bf, out_f, cls_bf, cls_f, b0, rs, rss);
}

// ---------------- attention, seqlen 9: 4 seqs / 320-thread block -----------------------
// R8 version: K,V-only LDS (36 KB -> 4 blocks/CU); q direct from global; dense ao out.
__global__ __launch_bounds__(320) void attn9_k(const bf16_t* __restrict__ qkv,
                                               bf16_t* __restrict__ ao) {
    __shared__ __align__(16) bf16_t kv[36 * 512];  // [s*9+j][ k(256) | v(256) ]
    int b = blockIdx.x; int tid = threadIdx.x;
    const bf16_t* src = qkv + (size_t)b * 27648;   // 36 rows x 768
    for (int c = tid; c < 2304; c += 320) {        // 36 rows x 64 chunks of 16B
        int row = c >> 6; int off = (c & 63) << 3;
        *(uint4*)&kv[row * 512 + off] = *(const uint4*)&src[row * 768 + 256 + off];
    }
    __syncthreads();
    if (tid < 288) {
        int s = tid / 72; int rem = tid - s * 72; int h = rem / 9; int i = rem - h * 9;
        const bf16_t* qp = src + (size_t)(s * 9 + i) * 768 + h * 32;
        float qf[32];
#pragma unroll
        for (int c = 0; c < 4; c++) {
            bf16x8 t8 = *(const bf16x8*)(qp + c * 8);
#pragma unroll
            for (int e = 0; e < 8; e++) qf[c * 8 + e] = (float)t8[e];
        }
        float sc[9]; float mx = -1e30f;
#pragma unroll
        for (int j = 0; j < 9; j++) {
            const bf16_t* kp = &kv[(s * 9 + j) * 512 + h * 32];
            float d = 0.f;
#pragma unroll
            for (int c = 0; c < 4; c++) {
                bf16x8 t8 = *(const bf16x8*)(kp + c * 8);
#pragma unroll
                for (int e = 0; e < 8; e++) d += qf[c * 8 + e] * (float)t8[e];
            }
            d *= 0.17677669529663687f;
            sc[j] = d; mx = fmaxf(mx, d);
        }
        float den = 0.f;
#pragma unroll
        for (int j = 0; j < 9; j++) { sc[j] = __expf(sc[j] - mx); den += sc[j]; }
        float inv = 1.0f / den;
        float of[32] = {};
#pragma unroll
        for (int j = 0; j < 9; j++) {
            const bf16_t* vp = &kv[(s * 9 + j) * 512 + 256 + h * 32];
            float w = sc[j];
#pragma unroll
            for (int c = 0; c < 4; c++) {
                bf16x8 t8 = *(const bf16x8*)(vp + c * 8);
#pragma unroll
                for (int e = 0; e < 8; e++) of[c * 8 + e] += w * (float)t8[e];
            }
        }
        bf16_t* dst = ao + ((size_t)(b * 4 + s) * 9 + i) * 256 + h * 32;
#pragma unroll
        for (int c = 0; c < 4; c++) {
            bf16x8 o8;
#pragma unroll
            for (int e = 0; e < 8; e++) o8[e] = (bf16_t)(of[c * 8 + e] * inv);
            *(bf16x8*)(dst + c * 8) = o8;
        }
    }
}

// ---------------- attention, seqlen 64 (stage C) ---------------------------------------
__global__ __launch_bounds__(256) void attn64_k(const bf16_t* __restrict__ qkv,
                                                bf16_t* __restrict__ ao) {
    __shared__ __align__(16) float kk[64 * 36];   // padded rows
    __shared__ __align__(16) float vv[64 * 36];
    __shared__ __align__(16) float pp[64 * 64];   // P[j][i]
    __shared__ float mloc[4 * 64];
    __shared__ float sloc[4 * 64];
    int s = blockIdx.x >> 3, h = blockIdx.x & 7;
    int t = threadIdx.x;
    int i = t & 63;
    int wq = t >> 6;

    {
        int r = t >> 2, c = t & 3;
        const bf16_t* kb = qkv + ((size_t)(s * 64 + r)) * 768 + h * 32 + 256 + c * 8;
        bf16x8 k8 = *(const bf16x8*)kb;
        bf16x8 v8 = *(const bf16x8*)(kb + 256);
        float* kd = &kk[r * 36 + c * 8];
        float* vd = &vv[r * 36 + c * 8];
#pragma unroll
        for (int e = 0; e < 8; e++) { kd[e] = (float)k8[e]; vd[e] = (float)v8[e]; }
    }
    const bf16_t* qb = qkv + ((size_t)(s * 64 + i)) * 768 + h * 32;
    float qf[32];
#pragma unroll
    for (int c = 0; c < 4; c++) {
        bf16x8 t8 = *(const bf16x8*)(qb + c * 8);
#pragma unroll
        for (int e = 0; e < 8; e++) qf[c * 8 + e] = (float)t8[e];
    }
    __syncthreads();

    float sc[16]; float mx = -1e30f;
#pragma unroll
    for (int jj = 0; jj < 16; jj++) {
        int j = wq * 16 + jj;
        const float* kr = &kk[j * 36];
        float d = 0.f;
#pragma unroll
        for (int c = 0; c < 8; c++) {
            float4 k4 = *(const float4*)(kr + c * 4);
            d += qf[c*4+0]*k4.x + qf[c*4+1]*k4.y + qf[c*4+2]*k4.z + qf[c*4+3]*k4.w;
        }
        d *= 0.17677669529663687f;
        sc[jj] = d; mx = fmaxf(mx, d);
    }
    float se = 0.f;
#pragma unroll
    for (int jj = 0; jj < 16; jj++) se += __expf(sc[jj] - mx);
    mloc[wq * 64 + i] = mx;
    sloc[wq * 64 + i] = se;
    __syncthreads();

    float m0 = mloc[i], m1 = mloc[64 + i], m2 = mloc[128 + i], m3 = mloc[192 + i];
    float gm = fmaxf(fmaxf(m0, m1), fmaxf(m2, m3));
    float D = sloc[i] * __expf(m0 - gm) + sloc[64 + i] * __expf(m1 - gm)
            + sloc[128 + i] * __expf(m2 - gm) + sloc[192 + i] * __expf(m3 - gm);

#pragma unroll
    for (int jj = 0; jj < 16; jj++)
        pp[(wq * 16 + jj) * 64 + i] = __expf(sc[jj] - gm);
    __syncthreads();

    float of[8] = {};
    for (int j = 0; j < 64; j++) {
        float w = pp[j * 64 + i];
        const float* vr = &vv[j * 36 + wq * 8];
        float4 va = *(const float4*)vr;
        float4 vb = *(const float4*)(vr + 4);
        of[0] += w * va.x; of[1] += w * va.y; of[2] += w * va.z; of[3] += w * va.w;
        of[4] += w * vb.x; of[5] += w * vb.y; of[6] += w * vb.z; of[7] += w * vb.w;
    }
    float invD = 1.0f / D;
    bf16_t o8[8];
#pragma unroll
    for (int e = 0; e < 8; e++) o8[e] = (bf16_t)(of[e] * invD);
    *(uint4*)(ao + ((size_t)(s * 64 + i)) * 256 + h * 32 + wq * 8) = *(uint4*)o8;
}

// ------------------------------------------------------------------------------------------
extern "C" void kernel_launch(void* const* d_in, const int* in_sizes, int n_in,
                              void* d_out, int out_size, void* d_ws, size_t ws_size,
                              hipStream_t stream) {
    const float* mv   = (const float*)d_in[0];
    const float* w_in = (const float*)d_in[2];
    const float* b_in = (const float*)d_in[3];
    const float* sp[12]; const float* tp[12];
    for (int i = 0; i < 12; i++) { sp[i] = (const float*)d_in[4 + i]; tp[i] = (const float*)d_in[16 + i]; }
    // idx: 0 qkvw, 1 qkvb, 2 ow, 3 ob, 4 l1w, 5 l1b, 6 l2w, 7 l2b, 8 ln1w, 9 ln1b, 10 ln2w, 11 ln2b

    bf16_t* wbf = (bf16_t*)d_ws;              // 1310720 bf16 weights
    bf16_t* txb = wbf + 1310720;              // t_x bf16: 16384*256
    float*  txf = (float*)(txb + 4194304);    // t_x fp32: 16384*256
    bf16_t* pool = (bf16_t*)(txf + 4194304);

    long long headB = 2621440LL + 8388608LL + 16777216LL;  // wbf + txb + txf bytes
    long long cand[5] = {16384, 8192, 4096, 2048, 1024};
    int BC = 1024;
    for (int c = 0; c < 5; c++) {
        long long poolB = cand[c] * 11520LL * 2;            // x(2304)+qkv(6912)+ao(2304) bf16
        if (poolB < 33554432LL) poolB = 33554432LL;         // stage-C floor
        if ((size_t)(headB + poolB) <= ws_size) { BC = (int)cand[c]; break; }
    }

    cvt_weights<<<5120, 256, 0, stream>>>(sp[0], sp[2], sp[4], sp[6], tp[0], tp[2], tp[4], tp[6], wbf);

    const int M = BC * 9;
    const int MT64 = M / 64;
    bf16_t* xc    = pool;
    bf16_t* qkvb_ = pool + (long long)BC * 2304;
    bf16_t* aob   = qkvb_ + (long long)BC * 6912;

    for (int b0 = 0; b0 < 16384; b0 += BC) {
        embed_k<<<dim3(M), 256, 0, stream>>>(mv, w_in, b_in, xc, b0);
        for (int l = 0; l < 2; l++) {
            const bf16_t* wq = wbf + 0      + l * 196608;
            const bf16_t* wo = wbf + 393216 + l * 65536;
            const bf16_t* w1 = wbf + 524288 + l * 32768;
            const bf16_t* w2 = wbf + 589824 + l * 32768;
            gemm_bt<<<dim3((M / 128) * 6), 256, 0, stream>>>(xc, wq, sp[1] + l * 768, qkvb_, M, 768, 256, 0);
            attn9_k<<<dim3(BC / 4), 320, 0, stream>>>(qkvb_, aob);
            gemm_proj_ln<<<dim3(MT64), 256, 0, stream>>>(aob, wo, sp[3] + l * 256,
                                                         xc, (const float*)nullptr,
                                                         sp[8] + l * 256, sp[9] + l * 256,
                                                         xc, (float*)nullptr);
            if (l == 0)
                gemm_ffn_ln<<<dim3(MT64), 256, 0, stream>>>(xc, w1, sp[5] + l * 128,
                                                            w2, sp[7] + l * 256,
                                                            sp[10] + l * 256, sp[11] + l * 256,
                                                            (const float*)nullptr,
                                                            xc, (float*)nullptr,
                                                            (bf16_t*)nullptr, (float*)nullptr, 0);
            else
                gemm_ffn_ln<<<dim3(MT64), 256, 0, stream>>>(xc, w1, sp[5] + l * 128,
                                                            w2, sp[7] + l * 256,
                                                            sp[10] + l * 256, sp[11] + l * 256,
                                                            (const float*)nullptr,
                                                            (bf16_t*)nullptr, (float*)nullptr,
                                                            txb, txf, b0);
        }
    }

    // ---- stage C: 256 seqs x 64 tokens, fp32 residual sidecar ----
    bf16_t* tqkv = pool;                    // 16384*768
    bf16_t* tao  = pool + 12582912;         // 16384*256
    for (int l = 0; l < 2; l++) {
        gemm_bt<<<dim3(128 * 6), 256, 0, stream>>>(txb, wbf + 655360 + l * 196608, tp[1] + l * 768,
                                                   tqkv, 16384, 768, 256, 0);
        attn64_k<<<dim3(2048), 256, 0, stream>>>(tqkv, tao);
        gemm_proj_ln<<<dim3(256), 256, 0, stream>>>(tao, wbf + 1048576 + l * 65536, tp[3] + l * 256,
                                                    (const bf16_t*)nullptr, txf,
                                                    tp[8] + l * 256, tp[9] + l * 256,
                                                    txb, txf);
        gemm_ffn_ln<<<dim3(256), 256, 0, stream>>>(txb, wbf + 1179648 + l * 32768, tp[5] + l * 128,
                                                   wbf + 1245184 + l * 32768, tp[7] + l * 256,
                                                   tp[10] + l * 256, tp[11] + l * 256,
                                                   txf,
                                                   (l == 0) ? txb : (bf16_t*)nullptr,
                                                   (l == 0) ? txf : (float*)d_out,
                                                   (bf16_t*)nullptr, (float*)nullptr, 0);
    }
}

// Round 11
// 961.348 us; speedup vs baseline: 1.1409x; 1.0991x over previous
//
#include <hip/hip_runtime.h>
#include <hip/hip_bf16.h>
#include <math.h>

typedef __bf16 bf16_t;
typedef float floatx4 __attribute__((ext_vector_type(4)));
typedef bf16_t bf16x8 __attribute__((ext_vector_type(8)));

typedef __attribute__((address_space(1))) void g_void;
typedef __attribute__((address_space(3))) void lds_void;

__device__ __forceinline__ void ldg_lds16(const bf16_t* g, bf16_t* l) {
    __builtin_amdgcn_global_load_lds((g_void*)g, (lds_void*)l, 16, 0, 0);
}

__device__ __forceinline__ void unpack4(uint2 r, float* o) {
    o[0] = __uint_as_float((r.x & 0xffffu) << 16); o[1] = __uint_as_float(r.x & 0xffff0000u);
    o[2] = __uint_as_float((r.y & 0xffffu) << 16); o[3] = __uint_as_float(r.y & 0xffff0000u);
}

// ---------------- weight fp32 -> bf16 conversion --------------------------------------
__global__ void cvt_weights(const float* __restrict__ sqkvw, const float* __restrict__ sow,
                            const float* __restrict__ sl1w,  const float* __restrict__ sl2w,
                            const float* __restrict__ tqkvw, const float* __restrict__ tow,
                            const float* __restrict__ tl1w,  const float* __restrict__ tl2w,
                            bf16_t* __restrict__ dst) {
    int i = blockIdx.x * 256 + threadIdx.x;  // total 1310720
    float v;
    if      (i <  393216) v = sqkvw[i];
    else if (i <  524288) v = sow  [i -  393216];
    else if (i <  589824) v = sl1w [i -  524288];
    else if (i <  655360) v = sl2w [i -  589824];
    else if (i < 1048576) v = tqkvw[i -  655360];
    else if (i < 1179648) v = tow  [i - 1048576];
    else if (i < 1245184) v = tl1w [i - 1179648];
    else                  v = tl2w [i - 1245184];
    dst[i] = (bf16_t)v;
}

// ---------------- embed: gelu(moveinfo @ w_in^T + b_in), cls=1e-5, layout [BC,9,256] ----
__global__ void embed_k(const float* __restrict__ mv, const float* __restrict__ w_in,
                        const float* __restrict__ b_in, bf16_t* __restrict__ x, int b0) {
    int blk = blockIdx.x; int d = threadIdx.x;
    int tok = blk % 9; int lb = blk / 9;
    size_t oidx = (size_t)blk * 256 + d;
    if (tok == 0) { x[oidx] = (bf16_t)1e-5f; return; }
    int bb = b0 + lb; int t = bb >> 8; int s = bb & 255;   // b = t*256+s
    int n = s * 8 + (tok - 1);
    float m0 = mv[((size_t)n * 64 + t) * 2];
    float m1 = mv[((size_t)n * 64 + t) * 2 + 1];
    float v = m0 * w_in[2 * d] + m1 * w_in[2 * d + 1] + b_in[d];
    v = 0.5f * v * (1.0f + erff(v * 0.70710678118654752f));  // exact gelu
    x[oidx] = (bf16_t)v;
}

// ---------------- plain GEMM: C = A @ W^T + bias (opt relu), bf16 out ------------------
// R2-exact version (measured 62.6-65 us): dual K-slab per barrier round (BK=64),
// 1-D grid XCD-grouped, swapped MFMA operands.
__global__ __launch_bounds__(256) void gemm_bt(const bf16_t* __restrict__ A,
                                               const bf16_t* __restrict__ W,
                                               const float* __restrict__ bias,
                                               bf16_t* __restrict__ C,
                                               int M, int N, int K, int relu) {
    __shared__ __align__(16) bf16_t As[8192];  // 2 slabs of [128][32]
    __shared__ __align__(16) bf16_t Ws[8192];
    int MT = M >> 7, NT = N >> 7;
    int g = blockIdx.x;
    int m_t, n_t;
    if ((MT & 7) == 0) {
        int x = g & 7, q = g >> 3;
        m_t = (q / NT) * 8 + x;
        n_t = q % NT;
    } else {
        m_t = g / NT; n_t = g % NT;
    }
    int tid = threadIdx.x;
    int lane = tid & 63;
    int wave = tid >> 6;
    int m0 = m_t * 128;
    int n0 = n_t * 128;
    int wm = (wave & 1) * 64;
    int wn = (wave >> 1) * 64;
    int arow = tid >> 2;
    int acol = (tid & 3) * 8;
    int fm = lane & 15;
    int fq = lane >> 4;

    floatx4 acc[4][4] = {};

    const bf16_t* Ag = A + (size_t)(m0 + arow) * K + acol;
    const bf16_t* Wg = W + (size_t)(n0 + arow) * K + acol;

    for (int k0 = 0; k0 < K; k0 += 64) {
        __syncthreads();
        ldg_lds16(Ag + k0,                       &As[tid * 8]);
        ldg_lds16(Ag + k0 + (size_t)64 * K,      &As[2048 + tid * 8]);
        ldg_lds16(Ag + k0 + 32,                  &As[4096 + tid * 8]);
        ldg_lds16(Ag + k0 + 32 + (size_t)64 * K, &As[6144 + tid * 8]);
        ldg_lds16(Wg + k0,                       &Ws[tid * 8]);
        ldg_lds16(Wg + k0 + (size_t)64 * K,      &Ws[2048 + tid * 8]);
        ldg_lds16(Wg + k0 + 32,                  &Ws[4096 + tid * 8]);
        ldg_lds16(Wg + k0 + 32 + (size_t)64 * K, &Ws[6144 + tid * 8]);
        __syncthreads();

#pragma unroll
        for (int sl = 0; sl < 2; sl++) {
            int base = sl * 4096;
            bf16x8 af[4], wf[4];
#pragma unroll
            for (int mi = 0; mi < 4; mi++)
                af[mi] = *(const bf16x8*)&As[base + (wm + mi * 16 + fm) * 32 + fq * 8];
#pragma unroll
            for (int ni = 0; ni < 4; ni++)
                wf[ni] = *(const bf16x8*)&Ws[base + (wn + ni * 16 + fm) * 32 + fq * 8];
#pragma unroll
            for (int mi = 0; mi < 4; mi++)
#pragma unroll
                for (int ni = 0; ni < 4; ni++)
                    acc[mi][ni] = __builtin_amdgcn_mfma_f32_16x16x32_bf16(wf[ni], af[mi], acc[mi][ni], 0, 0, 0);
        }
    }

#pragma unroll
    for (int mi = 0; mi < 4; mi++) {
        int row = m0 + wm + mi * 16 + fm;
#pragma unroll
        for (int ni = 0; ni < 4; ni++) {
            int colb = n0 + wn + ni * 16 + fq * 4;
            float4 b4 = *(const float4*)(bias + colb);
            float v0 = acc[mi][ni][0] + b4.x;
            float v1 = acc[mi][ni][1] + b4.y;
            float v2 = acc[mi][ni][2] + b4.z;
            float v3 = acc[mi][ni][3] + b4.w;
            if (relu) {
                v0 = fmaxf(v0, 0.f); v1 = fmaxf(v1, 0.f);
                v2 = fmaxf(v2, 0.f); v3 = fmaxf(v3, 0.f);
            }
            bf16_t t4[4] = {(bf16_t)v0, (bf16_t)v1, (bf16_t)v2, (bf16_t)v3};
            *(uint2*)(C + (size_t)row * N + colb) = *(uint2*)t4;
        }
    }
}

// ---------------- fused epilogue (BM=64): bias + residual + LN + store -----------------
// (stage C path) cls_bf/cls_f: optional extra store for rows%9==0 remapped to t_x layout.
__device__ __forceinline__ void epi_resln64(
    floatx4 (&acc)[4][4], int m0, int wn, int fm, int fq, int wave,
    const float* __restrict__ bias, const bf16_t* __restrict__ res_bf,
    const float* __restrict__ res_f, const float* __restrict__ lnw,
    const float* __restrict__ lnb, bf16_t* out_bf, float* out_f,
    bf16_t* cls_bf, float* cls_f, int b0,
    float (*rs)[64], float (*rss)[64]) {
    float s[4] = {0.f, 0.f, 0.f, 0.f}, ss[4] = {0.f, 0.f, 0.f, 0.f};
#pragma unroll
    for (int mi = 0; mi < 4; mi++) {
        size_t row = (size_t)(m0 + mi * 16 + fm);
#pragma unroll
        for (int ni = 0; ni < 4; ni++) {
            int col = wn + ni * 16 + fq * 4;
            float4 b4 = *(const float4*)(bias + col);
            float r4[4];
            if (res_f) {
                float4 t = *(const float4*)(res_f + row * 256 + col);
                r4[0] = t.x; r4[1] = t.y; r4[2] = t.z; r4[3] = t.w;
            } else {
                unpack4(*(const uint2*)(res_bf + row * 256 + col), r4);
            }
            float v0 = acc[mi][ni][0] + b4.x + r4[0];
            float v1 = acc[mi][ni][1] + b4.y + r4[1];
            float v2 = acc[mi][ni][2] + b4.z + r4[2];
            float v3 = acc[mi][ni][3] + b4.w + r4[3];
            acc[mi][ni][0] = v0; acc[mi][ni][1] = v1;
            acc[mi][ni][2] = v2; acc[mi][ni][3] = v3;
            s[mi] += v0 + v1 + v2 + v3;
            ss[mi] += v0 * v0 + v1 * v1 + v2 * v2 + v3 * v3;
        }
    }
#pragma unroll
    for (int mi = 0; mi < 4; mi++) {
        s[mi]  += __shfl_xor(s[mi], 16);  s[mi]  += __shfl_xor(s[mi], 32);
        ss[mi] += __shfl_xor(ss[mi], 16); ss[mi] += __shfl_xor(ss[mi], 32);
    }
    if (fq == 0) {
#pragma unroll
        for (int mi = 0; mi < 4; mi++) {
            rs [wave][mi * 16 + fm] = s[mi];
            rss[wave][mi * 16 + fm] = ss[mi];
        }
    }
    __syncthreads();
#pragma unroll
    for (int mi = 0; mi < 4; mi++) {
        int lrow = mi * 16 + fm;
        int grow = m0 + lrow;
        size_t row = (size_t)grow;
        float mean = (rs[0][lrow] + rs[1][lrow] + rs[2][lrow] + rs[3][lrow]) * (1.f / 256.f);
        float var  = (rss[0][lrow] + rss[1][lrow] + rss[2][lrow] + rss[3][lrow]) * (1.f / 256.f)
                   - mean * mean;
        float inv = rsqrtf(var + 1e-5f);
        int is_cls = (cls_bf != nullptr) && (grow % 9 == 0);
        size_t di = 0;
        if (is_cls) {
            int bb = b0 + grow / 9;
            int tt = bb >> 8, sseg = bb & 255;
            di = ((size_t)(sseg * 64 + tt)) * 256;
        }
#pragma unroll
        for (int ni = 0; ni < 4; ni++) {
            int col = wn + ni * 16 + fq * 4;
            float4 w4 = *(const float4*)(lnw + col);
            float4 bl = *(const float4*)(lnb + col);
            float o0 = (acc[mi][ni][0] - mean) * inv * w4.x + bl.x;
            float o1 = (acc[mi][ni][1] - mean) * inv * w4.y + bl.y;
            float o2 = (acc[mi][ni][2] - mean) * inv * w4.z + bl.z;
            float o3 = (acc[mi][ni][3] - mean) * inv * w4.w + bl.w;
            if (out_bf) {
                bf16_t t4[4] = {(bf16_t)o0, (bf16_t)o1, (bf16_t)o2, (bf16_t)o3};
                *(uint2*)(out_bf + row * 256 + col) = *(uint2*)t4;
            }
            if (out_f) {
                float4 t; t.x = o0; t.y = o1; t.z = o2; t.w = o3;
                *(float4*)(out_f + row * 256 + col) = t;
            }
            if (is_cls) {
                bf16_t t4[4] = {(bf16_t)o0, (bf16_t)o1, (bf16_t)o2, (bf16_t)o3};
                *(uint2*)(cls_bf + di + col) = *(uint2*)t4;
                float4 t; t.x = o0; t.y = o1; t.z = o2; t.w = o3;
                *(float4*)(cls_f + di + col) = t;
            }
        }
    }
}

// ---------------- STAGE A fused layer-tail: proj + LN1 + FFN + LN2 (+cls) -------------
// One block = 64 rows. x1 = LN1(x+attn@Wo) lives ONLY in LDS (saves 113 MB/layer of
// HBM round-trips). ffn1 reads X from LDS + w1 direct from L2; h reuses Ws region;
// ffn2 as before; LN2 residual from LDS. LDS 75 KB -> 2 blocks/CU.
__global__ __launch_bounds__(256) void proj_ffn_ln(const bf16_t* __restrict__ A,
                                                   const bf16_t* __restrict__ Wo,
                                                   const float* __restrict__ ob,
                                                   const bf16_t* __restrict__ res,
                                                   const float* __restrict__ ln1w,
                                                   const float* __restrict__ ln1b,
                                                   const bf16_t* __restrict__ w1,
                                                   const float* __restrict__ b1,
                                                   const bf16_t* __restrict__ w2,
                                                   const float* __restrict__ b2,
                                                   const float* __restrict__ ln2w,
                                                   const float* __restrict__ ln2b,
                                                   bf16_t* out_bf,
                                                   bf16_t* cls_bf, float* cls_f, int b0) {
    __shared__ __align__(16) bf16_t As[4096];      // 2 bufs [64][32]
    __shared__ __align__(16) bf16_t Ws[16384];     // proj W bufs; reused as Hs[10240]
    __shared__ __align__(16) bf16_t Xs[64 * 264];  // x1, padded (2-way banks only)
    __shared__ float rs[4][64], rss[4][64];
    int tid = threadIdx.x, lane = tid & 63, wave = tid >> 6;
    int m0 = blockIdx.x * 64;
    int wn = wave * 64;     // proj / ffn2 col stripe
    int wn1 = wave * 32;    // ffn1 col stripe
    int fm = lane & 15, fq = lane >> 4;

    // ---- proj GEMM (R5 pipelined BK=32) ----
    floatx4 acc[4][4] = {};
    {
        const bf16_t* Ag = A + (size_t)(m0 + (tid >> 2)) * 256 + (tid & 3) * 8;
        const bf16_t* Wg = Wo + (size_t)(tid >> 2) * 256 + (tid & 3) * 8;
        auto STAGE = [&](int r, int b) {
            int k = r * 32;
            ldg_lds16(Ag + k, &As[b * 2048 + tid * 8]);
#pragma unroll
            for (int j = 0; j < 4; j++)
                ldg_lds16(Wg + k + j * 16384, &Ws[b * 8192 + j * 2048 + tid * 8]);
        };
        auto COMPUTE = [&](int b) {
            bf16x8 af[4], wf[4];
#pragma unroll
            for (int mi = 0; mi < 4; mi++)
                af[mi] = *(const bf16x8*)&As[b * 2048 + (mi * 16 + fm) * 32 + fq * 8];
#pragma unroll
            for (int ni = 0; ni < 4; ni++)
                wf[ni] = *(const bf16x8*)&Ws[b * 8192 + (wn + ni * 16 + fm) * 32 + fq * 8];
#pragma unroll
            for (int mi = 0; mi < 4; mi++)
#pragma unroll
                for (int ni = 0; ni < 4; ni++)
                    acc[mi][ni] = __builtin_amdgcn_mfma_f32_16x16x32_bf16(wf[ni], af[mi], acc[mi][ni], 0, 0, 0);
        };
        STAGE(0, 0);
        __syncthreads();
        for (int r = 0; r < 7; ++r) {
            STAGE(r + 1, (r + 1) & 1);
            COMPUTE(r & 1);
            __syncthreads();
        }
        COMPUTE(1);
    }

    // ---- LN1 -> Xs (never touches HBM) ----
    {
        float s[4] = {0.f, 0.f, 0.f, 0.f}, ss[4] = {0.f, 0.f, 0.f, 0.f};
#pragma unroll
        for (int mi = 0; mi < 4; mi++) {
            size_t row = (size_t)(m0 + mi * 16 + fm);
#pragma unroll
            for (int ni = 0; ni < 4; ni++) {
                int col = wn + ni * 16 + fq * 4;
                float4 b4 = *(const float4*)(ob + col);
                float r4[4];
                unpack4(*(const uint2*)(res + row * 256 + col), r4);
                float v0 = acc[mi][ni][0] + b4.x + r4[0];
                float v1 = acc[mi][ni][1] + b4.y + r4[1];
                float v2 = acc[mi][ni][2] + b4.z + r4[2];
                float v3 = acc[mi][ni][3] + b4.w + r4[3];
                acc[mi][ni][0] = v0; acc[mi][ni][1] = v1;
                acc[mi][ni][2] = v2; acc[mi][ni][3] = v3;
                s[mi] += v0 + v1 + v2 + v3;
                ss[mi] += v0 * v0 + v1 * v1 + v2 * v2 + v3 * v3;
            }
        }
#pragma unroll
        for (int mi = 0; mi < 4; mi++) {
            s[mi]  += __shfl_xor(s[mi], 16);  s[mi]  += __shfl_xor(s[mi], 32);
            ss[mi] += __shfl_xor(ss[mi], 16); ss[mi] += __shfl_xor(ss[mi], 32);
        }
        if (fq == 0) {
#pragma unroll
            for (int mi = 0; mi < 4; mi++) {
                rs [wave][mi * 16 + fm] = s[mi];
                rss[wave][mi * 16 + fm] = ss[mi];
            }
        }
        __syncthreads();
#pragma unroll
        for (int mi = 0; mi < 4; mi++) {
            int lrow = mi * 16 + fm;
            float mean = (rs[0][lrow] + rs[1][lrow] + rs[2][lrow] + rs[3][lrow]) * (1.f / 256.f);
            float var  = (rss[0][lrow] + rss[1][lrow] + rss[2][lrow] + rss[3][lrow]) * (1.f / 256.f)
                       - mean * mean;
            float inv = rsqrtf(var + 1e-5f);
#pragma unroll
            for (int ni = 0; ni < 4; ni++) {
                int col = wn + ni * 16 + fq * 4;
                float4 w4 = *(const float4*)(ln1w + col);
                float4 bl = *(const float4*)(ln1b + col);
                bf16_t t4[4];
                t4[0] = (bf16_t)((acc[mi][ni][0] - mean) * inv * w4.x + bl.x);
                t4[1] = (bf16_t)((acc[mi][ni][1] - mean) * inv * w4.y + bl.y);
                t4[2] = (bf16_t)((acc[mi][ni][2] - mean) * inv * w4.z + bl.z);
                t4[3] = (bf16_t)((acc[mi][ni][3] - mean) * inv * w4.w + bl.w);
                *(uint2*)&Xs[lrow * 264 + col] = *(uint2*)t4;
            }
        }
    }
    __syncthreads();   // Xs visible; Ws reads long done -> reusable as Hs

    // ---- ffn1: h = relu(Xs @ w1^T + b1); no barriers; w1 from L2 ----
    floatx4 acc1[4][2] = {};
#pragma unroll
    for (int ks = 0; ks < 8; ks++) {
        bf16x8 af[4];
#pragma unroll
        for (int mi = 0; mi < 4; mi++)
            af[mi] = *(const bf16x8*)&Xs[(mi * 16 + fm) * 264 + ks * 32 + fq * 8];
#pragma unroll
        for (int ni = 0; ni < 2; ni++) {
            bf16x8 wf = *(const bf16x8*)(w1 + (size_t)(wn1 + ni * 16 + fm) * 256 + ks * 32 + fq * 8);
#pragma unroll
            for (int mi = 0; mi < 4; mi++)
                acc1[mi][ni] = __builtin_amdgcn_mfma_f32_16x16x32_bf16(wf, af[mi], acc1[mi][ni], 0, 0, 0);
        }
    }
    bf16_t* Hs = Ws;   // reuse proj weight buffers: Hs[4][64][40] = 10240 elems
#pragma unroll
    for (int mi = 0; mi < 4; mi++) {
        int row = mi * 16 + fm;
#pragma unroll
        for (int ni = 0; ni < 2; ni++) {
            int c = wn1 + ni * 16 + fq * 4;
            float4 b4 = *(const float4*)(b1 + c);
            bf16_t t4[4];
            t4[0] = (bf16_t)fmaxf(acc1[mi][ni][0] + b4.x, 0.f);
            t4[1] = (bf16_t)fmaxf(acc1[mi][ni][1] + b4.y, 0.f);
            t4[2] = (bf16_t)fmaxf(acc1[mi][ni][2] + b4.z, 0.f);
            t4[3] = (bf16_t)fmaxf(acc1[mi][ni][3] + b4.w, 0.f);
            *(uint2*)&Hs[(c >> 5) * 2560 + row * 40 + (c & 31)] = *(uint2*)t4;
        }
    }
    __syncthreads();

    // ---- ffn2: out = h @ w2^T; w2 from L2 ----
    floatx4 acc2[4][4] = {};
#pragma unroll
    for (int ks = 0; ks < 4; ks++) {
        bf16x8 af2[4];
#pragma unroll
        for (int mi = 0; mi < 4; mi++)
            af2[mi] = *(const bf16x8*)&Hs[ks * 2560 + (mi * 16 + fm) * 40 + fq * 8];
#pragma unroll
        for (int ni = 0; ni < 4; ni++) {
            bf16x8 wf2 = *(const bf16x8*)(w2 + (size_t)(wn + ni * 16 + fm) * 128 + ks * 32 + fq * 8);
#pragma unroll
            for (int mi = 0; mi < 4; mi++)
                acc2[mi][ni] = __builtin_amdgcn_mfma_f32_16x16x32_bf16(wf2, af2[mi], acc2[mi][ni], 0, 0, 0);
        }
    }

    // ---- LN2: residual from Xs; out -> xc (+cls remap for rows%9==0) ----
    {
        float s[4] = {0.f, 0.f, 0.f, 0.f}, ss[4] = {0.f, 0.f, 0.f, 0.f};
#pragma unroll
        for (int mi = 0; mi < 4; mi++) {
            int lrow = mi * 16 + fm;
#pragma unroll
            for (int ni = 0; ni < 4; ni++) {
                int col = wn + ni * 16 + fq * 4;
                float4 b4 = *(const float4*)(b2 + col);
                float r4[4];
                unpack4(*(const uint2*)&Xs[lrow * 264 + col], r4);
                float v0 = acc2[mi][ni][0] + b4.x + r4[0];
                float v1 = acc2[mi][ni][1] + b4.y + r4[1];
                float v2 = acc2[mi][ni][2] + b4.z + r4[2];
                float v3 = acc2[mi][ni][3] + b4.w + r4[3];
                acc2[mi][ni][0] = v0; acc2[mi][ni][1] = v1;
                acc2[mi][ni][2] = v2; acc2[mi][ni][3] = v3;
                s[mi] += v0 + v1 + v2 + v3;
                ss[mi] += v0 * v0 + v1 * v1 + v2 * v2 + v3 * v3;
            }
        }
#pragma unroll
        for (int mi = 0; mi < 4; mi++) {
            s[mi]  += __shfl_xor(s[mi], 16);  s[mi]  += __shfl_xor(s[mi], 32);
            ss[mi] += __shfl_xor(ss[mi], 16); ss[mi] += __shfl_xor(ss[mi], 32);
        }
        __syncthreads();   // protect rs/rss reuse (LN1 readers done long ago; uniform)
        if (fq == 0) {
#pragma unroll
            for (int mi = 0; mi < 4; mi++) {
                rs [wave][mi * 16 + fm] = s[mi];
                rss[wave][mi * 16 + fm] = ss[mi];
            }
        }
        __syncthreads();
#pragma unroll
        for (int mi = 0; mi < 4; mi++) {
            int lrow = mi * 16 + fm;
            int grow = m0 + lrow;
            size_t row = (size_t)grow;
            float mean = (rs[0][lrow] + rs[1][lrow] + rs[2][lrow] + rs[3][lrow]) * (1.f / 256.f);
            float var  = (rss[0][lrow] + rss[1][lrow] + rss[2][lrow] + rss[3][lrow]) * (1.f / 256.f)
                       - mean * mean;
            float inv = rsqrtf(var + 1e-5f);
            int is_cls = (cls_bf != nullptr) && (grow % 9 == 0);
            size_t di = 0;
            if (is_cls) {
                int bb = b0 + grow / 9;
                int tt = bb >> 8, sseg = bb & 255;
                di = ((size_t)(sseg * 64 + tt)) * 256;
            }
#pragma unroll
            for (int ni = 0; ni < 4; ni++) {
                int col = wn + ni * 16 + fq * 4;
                float4 w4 = *(const float4*)(ln2w + col);
                float4 bl = *(const float4*)(ln2b + col);
                float o0 = (acc2[mi][ni][0] - mean) * inv * w4.x + bl.x;
                float o1 = (acc2[mi][ni][1] - mean) * inv * w4.y + bl.y;
                float o2 = (acc2[mi][ni][2] - mean) * inv * w4.z + bl.z;
                float o3 = (acc2[mi][ni][3] - mean) * inv * w4.w + bl.w;
                if (out_bf) {
                    bf16_t t4[4] = {(bf16_t)o0, (bf16_t)o1, (bf16_t)o2, (bf16_t)o3};
                    *(uint2*)(out_bf + row * 256 + col) = *(uint2*)t4;
                }
                if (is_cls) {
                    bf16_t t4[4] = {(bf16_t)o0, (bf16_t)o1, (bf16_t)o2, (bf16_t)o3};
                    *(uint2*)(cls_bf + di + col) = *(uint2*)t4;
                    float4 t; t.x = o0; t.y = o1; t.z = o2; t.w = o3;
                    *(float4*)(cls_f + di + col) = t;
                }
            }
        }
    }
}

// ---------------- fused proj GEMM (stage C): + residual + LN, BM=64 --------------------
__global__ __launch_bounds__(256) void gemm_proj_ln(const bf16_t* __restrict__ A,
                                                    const bf16_t* __restrict__ W,
                                                    const float* __restrict__ bias,
                                                    const bf16_t* __restrict__ res_bf,
                                                    const float* __restrict__ res_f,
                                                    const float* __restrict__ lnw,
                                                    const float* __restrict__ lnb,
                                                    bf16_t* out_bf,
                                                    float* out_f) {
    __shared__ __align__(16) bf16_t As[4096];    // 2 bufs [64][32]
    __shared__ __align__(16) bf16_t Ws[16384];   // 2 bufs [256][32]
    __shared__ float rs[4][64], rss[4][64];
    int tid = threadIdx.x;
    int lane = tid & 63, wave = tid >> 6;
    int m0 = blockIdx.x * 64;
    int wn = wave * 64;
    int fm = lane & 15, fq = lane >> 4;
    floatx4 acc[4][4] = {};
    const bf16_t* Ag = A + (size_t)(m0 + (tid >> 2)) * 256 + (tid & 3) * 8;
    const bf16_t* Wg = W + (size_t)(tid >> 2) * 256 + (tid & 3) * 8;

    auto STAGE = [&](int r, int b) {
        int k = r * 32;
        ldg_lds16(Ag + k, &As[b * 2048 + tid * 8]);
#pragma unroll
        for (int j = 0; j < 4; j++)
            ldg_lds16(Wg + k + j * 16384, &Ws[b * 8192 + j * 2048 + tid * 8]);
    };
    auto COMPUTE = [&](int b) {
        bf16x8 af[4], wf[4];
#pragma unroll
        for (int mi = 0; mi < 4; mi++)
            af[mi] = *(const bf16x8*)&As[b * 2048 + (mi * 16 + fm) * 32 + fq * 8];
#pragma unroll
        for (int ni = 0; ni < 4; ni++)
            wf[ni] = *(const bf16x8*)&Ws[b * 8192 + (wn + ni * 16 + fm) * 32 + fq * 8];
#pragma unroll
        for (int mi = 0; mi < 4; mi++)
#pragma unroll
            for (int ni = 0; ni < 4; ni++)
                acc[mi][ni] = __builtin_amdgcn_mfma_f32_16x16x32_bf16(wf[ni], af[mi], acc[mi][ni], 0, 0, 0);
    };

    STAGE(0, 0);
    __syncthreads();
    for (int r = 0; r < 7; ++r) {
        STAGE(r + 1, (r + 1) & 1);
        COMPUTE(r & 1);
        __syncthreads();
    }
    COMPUTE(1);
    epi_resln64(acc, m0, wn, fm, fq, wave, bias, res_bf, res_f, lnw, lnb,
                out_bf, out_f, nullptr, nullptr, 0, rs, rss);
}

// ---------------- fused FFN (stage C): relu(X@w1^T+b1)@w2^T+b2 + residual + LN ---------
__global__ __launch_bounds__(256) void gemm_ffn_ln(const bf16_t* __restrict__ X,
                                                   const bf16_t* __restrict__ w1,
                                                   const float* __restrict__ b1,
                                                   const bf16_t* __restrict__ w2,
                                                   const float* __restrict__ b2,
                                                   const float* __restrict__ lnw,
                                                   const float* __restrict__ lnb,
                                                   const float* __restrict__ res_f,
                                                   bf16_t* out_bf, float* out_f,
                                                   bf16_t* cls_bf, float* cls_f, int b0) {
    __shared__ __align__(16) bf16_t As[4096];    // 2 bufs [64][32]
    __shared__ __align__(16) bf16_t Ws[8192];    // w1: 2 bufs [128][32]
    __shared__ __align__(16) bf16_t Hs[10240];   // 4 k-slabs [64][40]
    __shared__ float rs[4][64], rss[4][64];
    int tid = threadIdx.x, lane = tid & 63, wave = tid >> 6;
    int m0 = blockIdx.x * 64;
    int wn1 = wave * 32;
    int wn2 = wave * 64;
    int fm = lane & 15, fq = lane >> 4;
    floatx4 acc[4][2] = {};
    const bf16_t* Ag = X + (size_t)(m0 + (tid >> 2)) * 256 + (tid & 3) * 8;
    const bf16_t* Wg = w1 + (size_t)(tid >> 2) * 256 + (tid & 3) * 8;

    auto STAGE = [&](int r, int b) {
        int k = r * 32;
        ldg_lds16(Ag + k, &As[b * 2048 + tid * 8]);
#pragma unroll
        for (int j = 0; j < 2; j++)
            ldg_lds16(Wg + k + j * 16384, &Ws[b * 4096 + j * 2048 + tid * 8]);
    };
    auto COMPUTE = [&](int b) {
        bf16x8 af[4], wf[2];
#pragma unroll
        for (int mi = 0; mi < 4; mi++)
            af[mi] = *(const bf16x8*)&As[b * 2048 + (mi * 16 + fm) * 32 + fq * 8];
#pragma unroll
        for (int ni = 0; ni < 2; ni++)
            wf[ni] = *(const bf16x8*)&Ws[b * 4096 + (wn1 + ni * 16 + fm) * 32 + fq * 8];
#pragma unroll
        for (int mi = 0; mi < 4; mi++)
#pragma unroll
            for (int ni = 0; ni < 2; ni++)
                acc[mi][ni] = __builtin_amdgcn_mfma_f32_16x16x32_bf16(wf[ni], af[mi], acc[mi][ni], 0, 0, 0);
    };

    STAGE(0, 0);
    __syncthreads();
    for (int r = 0; r < 7; ++r) {
        STAGE(r + 1, (r + 1) & 1);
        COMPUTE(r & 1);
        __syncthreads();
    }
    COMPUTE(1);

#pragma unroll
    for (int mi = 0; mi < 4; mi++) {
        int row = mi * 16 + fm;
#pragma unroll
        for (int ni = 0; ni < 2; ni++) {
            int c = wn1 + ni * 16 + fq * 4;
            float4 b4 = *(const float4*)(b1 + c);
            bf16_t t4[4];
            t4[0] = (bf16_t)fmaxf(acc[mi][ni][0] + b4.x, 0.f);
            t4[1] = (bf16_t)fmaxf(acc[mi][ni][1] + b4.y, 0.f);
            t4[2] = (bf16_t)fmaxf(acc[mi][ni][2] + b4.z, 0.f);
            t4[3] = (bf16_t)fmaxf(acc[mi][ni][3] + b4.w, 0.f);
            *(uint2*)&Hs[(c >> 5) * 2560 + row * 40 + (c & 31)] = *(uint2*)t4;
        }
    }
    __syncthreads();
    floatx4 acc2[4][4] = {};
#pragma unroll
    for (int ks = 0; ks < 4; ks++) {
        bf16x8 af2[4];
#pragma unroll
        for (int mi = 0; mi < 4; mi++)
            af2[mi] = *(const bf16x8*)&Hs[ks * 2560 + (mi * 16 + fm) * 40 + fq * 8];
#pragma unroll
        for (int ni = 0; ni < 4; ni++) {
            bf16x8 wf2 = *(const bf16x8*)(w2 + (size_t)(wn2 + ni * 16 + fm) * 128 + ks * 32 + fq * 8);
#pragma unroll
            for (int mi = 0; mi < 4; mi++)
                acc2[mi][ni] = __builtin_amdgcn_mfma_f32_16x16x32_bf16(wf2, af2[mi], acc2[mi][ni], 0, 0, 0);
        }
    }
    epi_resln64(acc2, m0, wn2, fm, fq, wave, b2, X, res_f, lnw, lnb,
                out_bf, out_f, cls_bf, cls_f, b0, rs, rss);
}

// ---------------- attention, seqlen 9: 4 seqs / 320-thread block -----------------------
__global__ __launch_bounds__(320) void attn9_k(const bf16_t* __restrict__ qkv,
                                               bf16_t* __restrict__ ao) {
    __shared__ __align__(16) bf16_t kv[36 * 512];  // [s*9+j][ k(256) | v(256) ]
    int b = blockIdx.x; int tid = threadIdx.x;
    const bf16_t* src = qkv + (size_t)b * 27648;   // 36 rows x 768
    for (int c = tid; c < 2304; c += 320) {        // 36 rows x 64 chunks of 16B
        int row = c >> 6; int off = (c & 63) << 3;
        *(uint4*)&kv[row * 512 + off] = *(const uint4*)&src[row * 768 + 256 + off];
    }
    __syncthreads();
    if (tid < 288) {
        int s = tid / 72; int rem = tid - s * 72; int h = rem / 9; int i = rem - h * 9;
        const bf16_t* qp = src + (size_t)(s * 9 + i) * 768 + h * 32;
        float qf[32];
#pragma unroll
        for (int c = 0; c < 4; c++) {
            bf16x8 t8 = *(const bf16x8*)(qp + c * 8);
#pragma unroll
            for (int e = 0; e < 8; e++) qf[c * 8 + e] = (float)t8[e];
        }
        float sc[9]; float mx = -1e30f;
#pragma unroll
        for (int j = 0; j < 9; j++) {
            const bf16_t* kp = &kv[(s * 9 + j) * 512 + h * 32];
            float d = 0.f;
#pragma unroll
            for (int c = 0; c < 4; c++) {
                bf16x8 t8 = *(const bf16x8*)(kp + c * 8);
#pragma unroll
                for (int e = 0; e < 8; e++) d += qf[c * 8 + e] * (float)t8[e];
            }
            d *= 0.17677669529663687f;
            sc[j] = d; mx = fmaxf(mx, d);
        }
        float den = 0.f;
#pragma unroll
        for (int j = 0; j < 9; j++) { sc[j] = __expf(sc[j] - mx); den += sc[j]; }
        float inv = 1.0f / den;
        float of[32] = {};
#pragma unroll
        for (int j = 0; j < 9; j++) {
            const bf16_t* vp = &kv[(s * 9 + j) * 512 + 256 + h * 32];
            float w = sc[j];
#pragma unroll
            for (int c = 0; c < 4; c++) {
                bf16x8 t8 = *(const bf16x8*)(vp + c * 8);
#pragma unroll
                for (int e = 0; e < 8; e++) of[c * 8 + e] += w * (float)t8[e];
            }
        }
        bf16_t* dst = ao + ((size_t)(b * 4 + s) * 9 + i) * 256 + h * 32;
#pragma unroll
        for (int c = 0; c < 4; c++) {
            bf16x8 o8;
#pragma unroll
            for (int e = 0; e < 8; e++) o8[e] = (bf16_t)(of[c * 8 + e] * inv);
            *(bf16x8*)(dst + c * 8) = o8;
        }
    }
}

// ---------------- attention, seqlen 64 (stage C) ---------------------------------------
__global__ __launch_bounds__(256) void attn64_k(const bf16_t* __restrict__ qkv,
                                                bf16_t* __restrict__ ao) {
    __shared__ __align__(16) float kk[64 * 36];   // padded rows
    __shared__ __align__(16) float vv[64 * 36];
    __shared__ __align__(16) float pp[64 * 64];   // P[j][i]
    __shared__ float mloc[4 * 64];
    __shared__ float sloc[4 * 64];
    int s = blockIdx.x >> 3, h = blockIdx.x & 7;
    int t = threadIdx.x;
    int i = t & 63;
    int wq = t >> 6;

    {
        int r = t >> 2, c = t & 3;
        const bf16_t* kb = qkv + ((size_t)(s * 64 + r)) * 768 + h * 32 + 256 + c * 8;
        bf16x8 k8 = *(const bf16x8*)kb;
        bf16x8 v8 = *(const bf16x8*)(kb + 256);
        float* kd = &kk[r * 36 + c * 8];
        float* vd = &vv[r * 36 + c * 8];
#pragma unroll
        for (int e = 0; e < 8; e++) { kd[e] = (float)k8[e]; vd[e] = (float)v8[e]; }
    }
    const bf16_t* qb = qkv + ((size_t)(s * 64 + i)) * 768 + h * 32;
    float qf[32];
#pragma unroll
    for (int c = 0; c < 4; c++) {
        bf16x8 t8 = *(const bf16x8*)(qb + c * 8);
#pragma unroll
        for (int e = 0; e < 8; e++) qf[c * 8 + e] = (float)t8[e];
    }
    __syncthreads();

    float sc[16]; float mx = -1e30f;
#pragma unroll
    for (int jj = 0; jj < 16; jj++) {
        int j = wq * 16 + jj;
        const float* kr = &kk[j * 36];
        float d = 0.f;
#pragma unroll
        for (int c = 0; c < 8; c++) {
            float4 k4 = *(const float4*)(kr + c * 4);
            d += qf[c*4+0]*k4.x + qf[c*4+1]*k4.y + qf[c*4+2]*k4.z + qf[c*4+3]*k4.w;
        }
        d *= 0.17677669529663687f;
        sc[jj] = d; mx = fmaxf(mx, d);
    }
    float se = 0.f;
#pragma unroll
    for (int jj = 0; jj < 16; jj++) se += __expf(sc[jj] - mx);
    mloc[wq * 64 + i] = mx;
    sloc[wq * 64 + i] = se;
    __syncthreads();

    float m0 = mloc[i], m1 = mloc[64 + i], m2 = mloc[128 + i], m3 = mloc[192 + i];
    float gm = fmaxf(fmaxf(m0, m1), fmaxf(m2, m3));
    float D = sloc[i] * __expf(m0 - gm) + sloc[64 + i] * __expf(m1 - gm)
            + sloc[128 + i] * __expf(m2 - gm) + sloc[192 + i] * __expf(m3 - gm);

#pragma unroll
    for (int jj = 0; jj < 16; jj++)
        pp[(wq * 16 + jj) * 64 + i] = __expf(sc[jj] - gm);
    __syncthreads();

    float of[8] = {};
    for (int j = 0; j < 64; j++) {
        float w = pp[j * 64 + i];
        const float* vr = &vv[j * 36 + wq * 8];
        float4 va = *(const float4*)vr;
        float4 vb = *(const float4*)(vr + 4);
        of[0] += w * va.x; of[1] += w * va.y; of[2] += w * va.z; of[3] += w * va.w;
        of[4] += w * vb.x; of[5] += w * vb.y; of[6] += w * vb.z; of[7] += w * vb.w;
    }
    float invD = 1.0f / D;
    bf16_t o8[8];
#pragma unroll
    for (int e = 0; e < 8; e++) o8[e] = (bf16_t)(of[e] * invD);
    *(uint4*)(ao + ((size_t)(s * 64 + i)) * 256 + h * 32 + wq * 8) = *(uint4*)o8;
}

// ------------------------------------------------------------------------------------------
extern "C" void kernel_launch(void* const* d_in, const int* in_sizes, int n_in,
                              void* d_out, int out_size, void* d_ws, size_t ws_size,
                              hipStream_t stream) {
    const float* mv   = (const float*)d_in[0];
    const float* w_in = (const float*)d_in[2];
    const float* b_in = (const float*)d_in[3];
    const float* sp[12]; const float* tp[12];
    for (int i = 0; i < 12; i++) { sp[i] = (const float*)d_in[4 + i]; tp[i] = (const float*)d_in[16 + i]; }
    // idx: 0 qkvw, 1 qkvb, 2 ow, 3 ob, 4 l1w, 5 l1b, 6 l2w, 7 l2b, 8 ln1w, 9 ln1b, 10 ln2w, 11 ln2b

    bf16_t* wbf = (bf16_t*)d_ws;              // 1310720 bf16 weights
    bf16_t* txb = wbf + 1310720;              // t_x bf16: 16384*256
    float*  txf = (float*)(txb + 4194304);    // t_x fp32: 16384*256
    bf16_t* pool = (bf16_t*)(txf + 4194304);

    long long headB = 2621440LL + 8388608LL + 16777216LL;  // wbf + txb + txf bytes
    long long cand[5] = {16384, 8192, 4096, 2048, 1024};
    int BC = 1024;
    for (int c = 0; c < 5; c++) {
        long long poolB = cand[c] * 11520LL * 2;            // x(2304)+qkv(6912)+ao(2304) bf16
        if (poolB < 33554432LL) poolB = 33554432LL;         // stage-C floor
        if ((size_t)(headB + poolB) <= ws_size) { BC = (int)cand[c]; break; }
    }

    cvt_weights<<<5120, 256, 0, stream>>>(sp[0], sp[2], sp[4], sp[6], tp[0], tp[2], tp[4], tp[6], wbf);

    const int M = BC * 9;
    const int MT64 = M / 64;
    bf16_t* xc    = pool;
    bf16_t* qkvb_ = pool + (long long)BC * 2304;
    bf16_t* aob   = qkvb_ + (long long)BC * 6912;

    for (int b0 = 0; b0 < 16384; b0 += BC) {
        embed_k<<<dim3(M), 256, 0, stream>>>(mv, w_in, b_in, xc, b0);
        for (int l = 0; l < 2; l++) {
            const bf16_t* wq = wbf + 0      + l * 196608;
            const bf16_t* wo = wbf + 393216 + l * 65536;
            const bf16_t* w1 = wbf + 524288 + l * 32768;
            const bf16_t* w2 = wbf + 589824 + l * 32768;
            gemm_bt<<<dim3((M / 128) * 6), 256, 0, stream>>>(xc, wq, sp[1] + l * 768, qkvb_, M, 768, 256, 0);
            attn9_k<<<dim3(BC / 4), 320, 0, stream>>>(qkvb_, aob);
            proj_ffn_ln<<<dim3(MT64), 256, 0, stream>>>(aob, wo, sp[3] + l * 256,
                                                        xc, sp[8] + l * 256, sp[9] + l * 256,
                                                        w1, sp[5] + l * 128,
                                                        w2, sp[7] + l * 256,
                                                        sp[10] + l * 256, sp[11] + l * 256,
                                                        (l == 0) ? xc : (bf16_t*)nullptr,
                                                        (l == 0) ? (bf16_t*)nullptr : txb,
                                                        (l == 0) ? (float*)nullptr : txf, b0);
        }
    }

    // ---- stage C: 256 seqs x 64 tokens, fp32 residual sidecar ----
    bf16_t* tqkv = pool;                    // 16384*768
    bf16_t* tao  = pool + 12582912;         // 16384*256
    for (int l = 0; l < 2; l++) {
        gemm_bt<<<dim3(128 * 6), 256, 0, stream>>>(txb, wbf + 655360 + l * 196608, tp[1] + l * 768,
                                                   tqkv, 16384, 768, 256, 0);
        attn64_k<<<dim3(2048), 256, 0, stream>>>(tqkv, tao);
        gemm_proj_ln<<<dim3(256), 256, 0, stream>>>(tao, wbf + 1048576 + l * 65536, tp[3] + l * 256,
                                                    (const bf16_t*)nullptr, txf,
                                                    tp[8] + l * 256, tp[9] + l * 256,
                                                    txb, txf);
        gemm_ffn_ln<<<dim3(256), 256, 0, stream>>>(txb, wbf + 1179648 + l * 32768, tp[5] + l * 128,
                                                   wbf + 1245184 + l * 32768, tp[7] + l * 256,
                                                   tp[10] + l * 256, tp[11] + l * 256,
                                                   txf,
                                                   (l == 0) ? txb : (bf16_t*)nullptr,
                                                   (l == 0) ? txf : (float*)d_out,
                                                   (bf16_t*)nullptr, (float*)nullptr, 0);
    }
}